// Round 2
// baseline (3446.742 us; speedup 1.0000x reference)
//
#include <hip/hip_runtime.h>
#include <math.h>
#include <type_traits>

#define RESF 28
#define RESH 14
#define NH 16
#define KDIM 32
#define VDIM 64
#define CIN 512
#define NKV 1536   // NH*(KDIM+VDIM)
#define NQC 512    // NH*KDIM
#define NP 768
#define DH 1024    // NH*VDIM
#define NTOK 784
#define NTOKH 196
#define NB 64
#define MKV (NB*NTOK)    // 50176
#define MQ  (NB*NTOKH)   // 12544
#define BN_EPS 1e-5f
#define LOG2E 1.44269504088896f

// ---------------- bf16 helpers (raw ushort bits, RNE) ----------------
__device__ inline unsigned short f2bf(float f) {
  unsigned int u = __float_as_uint(f);
  unsigned int r = u + 0x7fffu + ((u >> 16) & 1u);
  return (unsigned short)(r >> 16);
}
__device__ inline float bf2f(unsigned short h) {
  return __uint_as_float(((unsigned int)h) << 16);
}

// ------------------------------------------------------------------
// biasT[h][j][r] = attn_biases[h, bias_idxs[r, j]] * LOG2E
// ------------------------------------------------------------------
__global__ void make_biasT(const float* __restrict__ ab, const int* __restrict__ idxs,
                           float* __restrict__ biasT, int n_off) {
  const int total = NH * NTOK * NTOKH;
  for (int idx = blockIdx.x * blockDim.x + threadIdx.x; idx < total;
       idx += gridDim.x * blockDim.x) {
    int r = idx % NTOKH;
    int j = (idx / NTOKH) % NTOK;
    int h = idx / (NTOKH * NTOK);
    biasT[idx] = ab[(size_t)h * n_off + idxs[r * NTOK + j]] * LOG2E;
  }
}

// ------------------------------------------------------------------
// GEMM: C[m,n] = sum_k A[m,k] * B[n,k]
// A: MxK row-major (fp32), B: NxK row-major (fp32), C: MxN (TC).
// GATHER=1: A row m maps to the ::2,::2 subsample of x (28x28 -> 14x14).
// 256 threads, 128x128 tile, 8x8 per thread, double-buffered LDS.
// ------------------------------------------------------------------
template <typename TC, int GATHER>
__global__ __launch_bounds__(256)
void gemm_nt(const float* __restrict__ A, const float* __restrict__ Bm,
             TC* __restrict__ C, int M, int N, int K) {
  __shared__ float As[2][16][132];
  __shared__ float Bs[2][16][132];
  const int t = threadIdx.x;
  const int tx = t & 15, ty = t >> 4;
  const int m0 = blockIdx.x * 128, n0 = blockIdx.y * 128;
  const int lr = t >> 2, lk = (t & 3) * 4;

  int rowA0 = m0 + lr, rowA1 = m0 + lr + 64;
  if (GATHER) {
    int b0 = rowA0 / NTOKH, r0 = rowA0 - b0 * NTOKH;
    int i0 = r0 / RESH, j0 = r0 - i0 * RESH;
    rowA0 = b0 * NTOK + i0 * (2 * RESF) + j0 * 2;
    int b1 = rowA1 / NTOKH, r1 = rowA1 - b1 * NTOKH;
    int i1 = r1 / RESH, j1 = r1 - i1 * RESH;
    rowA1 = b1 * NTOK + i1 * (2 * RESF) + j1 * 2;
  }
  const float* Apa = A + (size_t)rowA0 * K + lk;
  const float* Apb = A + (size_t)rowA1 * K + lk;
  const float* Bpa = Bm + (size_t)(n0 + lr) * K + lk;
  const float* Bpb = Bm + (size_t)(n0 + lr + 64) * K + lk;

  float4 pa0, pa1, pb0, pb1;
  auto loadAB = [&](int k0) {
    pa0 = *(const float4*)(Apa + k0);
    pa1 = *(const float4*)(Apb + k0);
    pb0 = *(const float4*)(Bpa + k0);
    pb1 = *(const float4*)(Bpb + k0);
  };
  auto storeAB = [&](int buf) {
    As[buf][lk + 0][lr] = pa0.x; As[buf][lk + 1][lr] = pa0.y;
    As[buf][lk + 2][lr] = pa0.z; As[buf][lk + 3][lr] = pa0.w;
    As[buf][lk + 0][lr + 64] = pa1.x; As[buf][lk + 1][lr + 64] = pa1.y;
    As[buf][lk + 2][lr + 64] = pa1.z; As[buf][lk + 3][lr + 64] = pa1.w;
    Bs[buf][lk + 0][lr] = pb0.x; Bs[buf][lk + 1][lr] = pb0.y;
    Bs[buf][lk + 2][lr] = pb0.z; Bs[buf][lk + 3][lr] = pb0.w;
    Bs[buf][lk + 0][lr + 64] = pb1.x; Bs[buf][lk + 1][lr + 64] = pb1.y;
    Bs[buf][lk + 2][lr + 64] = pb1.z; Bs[buf][lk + 3][lr + 64] = pb1.w;
  };

  float acc[8][8];
#pragma unroll
  for (int i = 0; i < 8; ++i)
#pragma unroll
    for (int j = 0; j < 8; ++j) acc[i][j] = 0.f;

  loadAB(0);
  storeAB(0);
  __syncthreads();

  const int nt = K / 16;
  for (int tt = 0; tt < nt; ++tt) {
    const int buf = tt & 1;
    if (tt + 1 < nt) loadAB((tt + 1) * 16);
#pragma unroll
    for (int kk = 0; kk < 16; ++kk) {
      float a[8], b[8];
      *(float4*)&a[0] = *(const float4*)&As[buf][kk][ty * 8];
      *(float4*)&a[4] = *(const float4*)&As[buf][kk][ty * 8 + 4];
      *(float4*)&b[0] = *(const float4*)&Bs[buf][kk][tx * 8];
      *(float4*)&b[4] = *(const float4*)&Bs[buf][kk][tx * 8 + 4];
#pragma unroll
      for (int i = 0; i < 8; ++i)
#pragma unroll
        for (int j = 0; j < 8; ++j) acc[i][j] = fmaf(a[i], b[j], acc[i][j]);
    }
    if (tt + 1 < nt) storeAB(buf ^ 1);
    __syncthreads();
  }

#pragma unroll
  for (int i = 0; i < 8; ++i) {
    const size_t off = (size_t)(m0 + ty * 8 + i) * N + n0 + tx * 8;
    if constexpr (std::is_same<TC, float>::value) {
      *(float4*)&C[off] = make_float4(acc[i][0], acc[i][1], acc[i][2], acc[i][3]);
      *(float4*)&C[off + 4] = make_float4(acc[i][4], acc[i][5], acc[i][6], acc[i][7]);
    } else {
      unsigned short h[8];
#pragma unroll
      for (int j = 0; j < 8; ++j) h[j] = f2bf(acc[i][j]);
      *(uint4*)&C[off] = *(uint4*)h;  // 8 bf16 = 16B, offset %8 elems -> 16B aligned
    }
  }
}

// ------------------------------------------------------------------
// Column stats (two stage). Stage 1: partial sum/sumsq (double) per
// (chunk, col). grid = (NC/64, 64 chunks), block = 256 (64 cols x 4).
// ------------------------------------------------------------------
template <typename TY>
__global__ void col_stats_partial(const TY* __restrict__ Y, double2* __restrict__ part,
                                  int M, int NC) {
  const int col = blockIdx.x * 64 + (threadIdx.x & 63);
  const int rs = threadIdx.x >> 6;
  const int chunk = blockIdx.y;
  const int rpc = (M + 63) / 64;
  const int r0 = chunk * rpc;
  const int r1 = (r0 + rpc < M) ? (r0 + rpc) : M;
  double s = 0.0, s2 = 0.0;
  for (int r = r0 + rs; r < r1; r += 4) {
    float v;
    if constexpr (std::is_same<TY, float>::value) v = Y[(size_t)r * NC + col];
    else v = bf2f(Y[(size_t)r * NC + col]);
    s += (double)v;
    s2 += (double)v * (double)v;
  }
  __shared__ double sh[2][4][64];
  sh[0][rs][threadIdx.x & 63] = s;
  sh[1][rs][threadIdx.x & 63] = s2;
  __syncthreads();
  if (threadIdx.x < 64) {
    int c = threadIdx.x;
    double ts = sh[0][0][c] + sh[0][1][c] + sh[0][2][c] + sh[0][3][c];
    double t2 = sh[1][0][c] + sh[1][1][c] + sh[1][2][c] + sh[1][3][c];
    part[(size_t)chunk * NC + col] = make_double2(ts, t2);
  }
}

// Stage 2: A = g/sqrt(var+eps)*mul, C = (b - mean*A0)*mul
__global__ void col_stats_finalize(const double2* __restrict__ part,
                                   const float* __restrict__ g, const float* __restrict__ bb,
                                   float* __restrict__ Aout, float* __restrict__ Cout,
                                   int NC, int M, float mul) {
  const int col = blockIdx.x * blockDim.x + threadIdx.x;
  if (col >= NC) return;
  double s = 0.0, s2 = 0.0;
  for (int ch = 0; ch < 64; ++ch) {
    double2 p = part[(size_t)ch * NC + col];
    s += p.x;
    s2 += p.y;
  }
  double mean = s / (double)M;
  double var = s2 / (double)M - mean * mean;
  double A0 = (double)g[col] / sqrt(var + (double)BN_EPS);
  Aout[col] = (float)(A0 * (double)mul);
  Cout[col] = (float)(((double)bb[col] - mean * A0) * (double)mul);
}

// ------------------------------------------------------------------
// Flash attention per (b,h). 256 threads, thread t<196 owns q-row t.
// q pre-scaled by BN-affine * scale * log2e (folded into Aq/Cq).
// bias already *log2e. Online softmax in exp2 domain, defer-max(8).
// ------------------------------------------------------------------
#define TJ 112
__device__ inline float hswish(float x) {
  float r = fminf(fmaxf(x + 3.f, 0.f), 6.f);
  return x * r * (1.f / 6.f);
}

template <typename TY>
__global__ __launch_bounds__(256)
void attn_kernel(const TY* __restrict__ Ykv, const float* __restrict__ Yq,
                 const float* __restrict__ biasT,
                 const float* __restrict__ Akv, const float* __restrict__ Ckv,
                 const float* __restrict__ Aq, const float* __restrict__ Cq,
                 float* __restrict__ Out) {
  const int b = blockIdx.x, h = blockIdx.y;
  const int t = threadIdx.x;
  __shared__ float ks[TJ][KDIM];
  __shared__ float vs[TJ][VDIM];
  __shared__ float akv_s[96], ckv_s[96];

  if (t < 96) {
    akv_s[t] = Akv[h * 96 + t];
    ckv_s[t] = Ckv[h * 96 + t];
  }

  float q[KDIM];
  if (t < NTOKH) {
    const float* qp = &Yq[((size_t)b * NTOKH + t) * NQC + h * KDIM];
#pragma unroll
    for (int d = 0; d < KDIM; d += 4) {
      float4 v4 = *(const float4*)&qp[d];
      q[d + 0] = v4.x * Aq[h * KDIM + d + 0] + Cq[h * KDIM + d + 0];
      q[d + 1] = v4.y * Aq[h * KDIM + d + 1] + Cq[h * KDIM + d + 1];
      q[d + 2] = v4.z * Aq[h * KDIM + d + 2] + Cq[h * KDIM + d + 2];
      q[d + 3] = v4.w * Aq[h * KDIM + d + 3] + Cq[h * KDIM + d + 3];
    }
  }

  float m_run = -1e30f, l_run = 0.f;
  float acc[VDIM];
#pragma unroll
  for (int d = 0; d < VDIM; ++d) acc[d] = 0.f;

  for (int tile = 0; tile < NTOK / TJ; ++tile) {
    const int n0 = tile * TJ;
    __syncthreads();  // previous tile consumed (covers akv_s on tile 0)
    for (int idx = t; idx < TJ * 24; idx += 256) {
      int row = idx / 24;
      int c4 = (idx % 24) * 4;
      const TY* src = &Ykv[((size_t)(b * NTOK + n0 + row)) * NKV + h * 96 + c4];
      float vv[4];
      if constexpr (std::is_same<TY, float>::value) {
        float4 v4 = *(const float4*)src;
        vv[0] = v4.x; vv[1] = v4.y; vv[2] = v4.z; vv[3] = v4.w;
      } else {
        ushort4 u4 = *(const ushort4*)src;
        vv[0] = bf2f(u4.x); vv[1] = bf2f(u4.y); vv[2] = bf2f(u4.z); vv[3] = bf2f(u4.w);
      }
#pragma unroll
      for (int i = 0; i < 4; ++i) {
        int ch = c4 + i;
        float nv = vv[i] * akv_s[ch] + ckv_s[ch];
        if (ch < KDIM) ks[row][ch] = nv;
        else vs[row][ch - KDIM] = nv;
      }
    }
    __syncthreads();

    float bcur = 0.f;
    if (t < NTOKH) bcur = biasT[((size_t)h * NTOK + n0) * NTOKH + t];
    for (int j = 0; j < TJ; ++j) {
      float bnext = 0.f;
      if (t < NTOKH && j + 1 < TJ)
        bnext = biasT[((size_t)h * NTOK + n0 + j + 1) * NTOKH + t];
      if (t < NTOKH) {
        float s = bcur;
#pragma unroll
        for (int kk = 0; kk < KDIM; kk += 4) {
          float4 k4 = *(const float4*)&ks[j][kk];
          s = fmaf(q[kk + 0], k4.x, s);
          s = fmaf(q[kk + 1], k4.y, s);
          s = fmaf(q[kk + 2], k4.z, s);
          s = fmaf(q[kk + 3], k4.w, s);
        }
        float p;
        if (s > m_run + 8.f) {  // rescale (rare)
          float corr = __builtin_exp2f(m_run - s);
          l_run *= corr;
#pragma unroll
          for (int d = 0; d < VDIM; ++d) acc[d] *= corr;
          m_run = s;
          p = 1.f;
        } else {
          p = __builtin_exp2f(s - m_run);
        }
        l_run += p;
#pragma unroll
        for (int d = 0; d < VDIM; d += 4) {
          float4 v4 = *(const float4*)&vs[j][d];
          acc[d + 0] = fmaf(p, v4.x, acc[d + 0]);
          acc[d + 1] = fmaf(p, v4.y, acc[d + 1]);
          acc[d + 2] = fmaf(p, v4.z, acc[d + 2]);
          acc[d + 3] = fmaf(p, v4.w, acc[d + 3]);
        }
      }
      bcur = bnext;
    }
  }

  if (t < NTOKH) {
    float inv = 1.f / l_run;
    float* op = &Out[((size_t)b * NTOKH + t) * DH + h * VDIM];
#pragma unroll
    for (int d = 0; d < VDIM; d += 4) {
      float4 o;
      o.x = hswish(acc[d + 0] * inv);
      o.y = hswish(acc[d + 1] * inv);
      o.z = hswish(acc[d + 2] * inv);
      o.w = hswish(acc[d + 3] * inv);
      *(float4*)&op[d] = o;
    }
  }
}

// ------------------------------------------------------------------
// Final normalize: out = Yp * Ap[c] + Cp[c]
// ------------------------------------------------------------------
__global__ void norm_out(const float* __restrict__ Yp, const float* __restrict__ Ap,
                         const float* __restrict__ Cp, float* __restrict__ out) {
  const int total = MQ * (NP / 4);
  for (int idx = blockIdx.x * blockDim.x + threadIdx.x; idx < total;
       idx += gridDim.x * blockDim.x) {
    int c4 = (idx % (NP / 4)) * 4;
    float4 y = ((const float4*)Yp)[idx];
    float4 o;
    o.x = y.x * Ap[c4 + 0] + Cp[c4 + 0];
    o.y = y.y * Ap[c4 + 1] + Cp[c4 + 1];
    o.z = y.z * Ap[c4 + 2] + Cp[c4 + 2];
    o.w = y.w * Ap[c4 + 3] + Cp[c4 + 3];
    ((float4*)out)[idx] = o;
  }
}

// ------------------------------------------------------------------
// Sizes in float units
static constexpr size_t SZ_YKV  = (size_t)MKV * NKV;       // 77,070,336
static constexpr size_t SZ_YQ   = (size_t)MQ * NQC;        //  6,422,528
static constexpr size_t SZ_OUT  = (size_t)MQ * DH;         // 12,845,056
static constexpr size_t SZ_BIAS = (size_t)NH * NTOK * NTOKH; // 2,458,624
static constexpr size_t SZ_PART = (size_t)64 * NKV * 4;    // 64*NKV double2
static constexpr size_t SZ_AC   = 2 * NKV + 2 * NQC + 2 * NP;

template <typename TKV>
static void run_pipeline(const float* x, const float* W_kv, const float* g_kv, const float* b_kv,
                         const float* W_q, const float* g_q, const float* b_q,
                         const float* W_proj, const float* g_proj, const float* b_proj,
                         const float* attn_b, const int* bias_idxs, int n_off,
                         float* ws, float* d_out, hipStream_t stream) {
  // layout (float units). KV occupies SZ_YKV elements of TKV.
  const size_t kv_fl = (SZ_YKV * sizeof(TKV)) / sizeof(float);
  TKV* Ykv = (TKV*)ws;
  float* Yq = ws + kv_fl;
  float* Out = Yq + SZ_YQ;
  float* BiasT = Out + SZ_OUT;
  double2* part = (double2*)(BiasT + SZ_BIAS);
  float* AC = (float*)(part + (size_t)64 * NKV);
  float* Akv = AC;            float* Ckv = AC + NKV;
  float* Aq = AC + 2 * NKV;   float* Cq = AC + 2 * NKV + NQC;
  float* Ap = AC + 2 * NKV + 2 * NQC;
  float* Cp = AC + 2 * NKV + 2 * NQC + NP;
  float* Yp = ws;  // aliases Ykv (dead after attention)

  const float qmul = 0.17677669529663687f * LOG2E;  // KD^-0.5 * log2(e)

  make_biasT<<<dim3(2048), dim3(256), 0, stream>>>(attn_b, bias_idxs, BiasT, n_off);

  gemm_nt<TKV, 0><<<dim3(MKV / 128, NKV / 128), dim3(256), 0, stream>>>(x, W_kv, Ykv, MKV, NKV, CIN);
  gemm_nt<float, 1><<<dim3(MQ / 128, NQC / 128), dim3(256), 0, stream>>>(x, W_q, Yq, MQ, NQC, CIN);

  col_stats_partial<TKV><<<dim3(NKV / 64, 64), dim3(256), 0, stream>>>(Ykv, part, MKV, NKV);
  col_stats_finalize<<<dim3(NKV / 256), dim3(256), 0, stream>>>(part, g_kv, b_kv, Akv, Ckv, NKV, MKV, 1.0f);
  col_stats_partial<float><<<dim3(NQC / 64, 64), dim3(256), 0, stream>>>(Yq, part, MQ, NQC);
  col_stats_finalize<<<dim3(NQC / 256), dim3(256), 0, stream>>>(part, g_q, b_q, Aq, Cq, NQC, MQ, qmul);

  attn_kernel<TKV><<<dim3(NB, NH), dim3(256), 0, stream>>>(Ykv, Yq, BiasT, Akv, Ckv, Aq, Cq, Out);

  gemm_nt<float, 0><<<dim3(MQ / 128, NP / 128), dim3(256), 0, stream>>>(Out, W_proj, Yp, MQ, NP, DH);
  col_stats_partial<float><<<dim3(NP / 64, 64), dim3(256), 0, stream>>>(Yp, part, MQ, NP);
  col_stats_finalize<<<dim3(NP / 256), dim3(256), 0, stream>>>(part, g_proj, b_proj, Ap, Cp, NP, MQ, 1.0f);

  norm_out<<<dim3(2048), dim3(256), 0, stream>>>(Yp, Ap, Cp, d_out);
}

extern "C" void kernel_launch(void* const* d_in, const int* in_sizes, int n_in,
                              void* d_out, int out_size, void* d_ws, size_t ws_size,
                              hipStream_t stream) {
  const float* x      = (const float*)d_in[0];
  const float* W_kv   = (const float*)d_in[1];
  const float* g_kv   = (const float*)d_in[2];
  const float* b_kv   = (const float*)d_in[3];
  const float* W_q    = (const float*)d_in[4];
  const float* g_q    = (const float*)d_in[5];
  const float* b_q    = (const float*)d_in[6];
  const float* W_proj = (const float*)d_in[7];
  const float* g_proj = (const float*)d_in[8];
  const float* b_proj = (const float*)d_in[9];
  const float* attn_b = (const float*)d_in[10];
  const int* bias_idxs = (const int*)d_in[11];
  const int n_off = in_sizes[10] / NH;

  const size_t need_f32 =
      (SZ_YKV + SZ_YQ + SZ_OUT + SZ_BIAS + SZ_PART + SZ_AC) * sizeof(float);

  if (ws_size >= need_f32) {
    run_pipeline<float>(x, W_kv, g_kv, b_kv, W_q, g_q, b_q, W_proj, g_proj, b_proj,
                        attn_b, bias_idxs, n_off, (float*)d_ws, (float*)d_out, stream);
  } else {
    run_pipeline<unsigned short>(x, W_kv, g_kv, b_kv, W_q, g_q, b_q, W_proj, g_proj, b_proj,
                                 attn_b, bias_idxs, n_off, (float*)d_ws, (float*)d_out, stream);
  }
}

// Round 4
// 2252.602 us; speedup vs baseline: 1.5301x; 1.5301x over previous
//
#include <hip/hip_runtime.h>
#include <math.h>
#include <type_traits>

#define RESF 28
#define RESH 14
#define NH 16
#define KDIM 32
#define VDIM 64
#define CIN 512
#define NKV 1536   // NH*(KDIM+VDIM)
#define NQC 512    // NH*KDIM
#define NP 768
#define DH 1024    // NH*VDIM
#define NTOK 784
#define NTOKH 196
#define NB 64
#define MKV (NB*NTOK)    // 50176
#define MQ  (NB*NTOKH)   // 12544
#define BN_EPS 1e-5f
#define LOG2E 1.44269504088896f

typedef __attribute__((ext_vector_type(8))) short bf16x8;
typedef __attribute__((ext_vector_type(4))) float f32x4;

// ---------------- bf16 helpers (raw ushort bits) ----------------
__device__ inline unsigned short f2bf(float f) {  // RNE
  unsigned int u = __float_as_uint(f);
  unsigned int r = u + 0x7fffu + ((u >> 16) & 1u);
  return (unsigned short)(r >> 16);
}
__device__ inline float bf2f(unsigned short h) {
  return __uint_as_float(((unsigned int)h) << 16);
}

// split 8 floats -> packed bf16 hi (RNE) and lo (truncated residual)
__device__ inline void split8(const float4 f0, const float4 f1, uint4& hi, uint4& lo) {
  float f[8] = {f0.x, f0.y, f0.z, f0.w, f1.x, f1.y, f1.z, f1.w};
  unsigned hh[8], ll[8];
#pragma unroll
  for (int i = 0; i < 8; ++i) {
    unsigned u = __float_as_uint(f[i]);
    unsigned r = u + 0x7fffu + ((u >> 16) & 1u);
    unsigned h = r >> 16;
    hh[i] = h;
    float rf = f[i] - __uint_as_float(h << 16);
    ll[i] = __float_as_uint(rf) >> 16;
  }
  hi = make_uint4(hh[0] | (hh[1] << 16), hh[2] | (hh[3] << 16),
                  hh[4] | (hh[5] << 16), hh[6] | (hh[7] << 16));
  lo = make_uint4(ll[0] | (ll[1] << 16), ll[2] | (ll[3] << 16),
                  ll[4] | (ll[5] << 16), ll[6] | (ll[7] << 16));
}

// ------------------------------------------------------------------
__global__ void split_w(const float* __restrict__ src, unsigned short* __restrict__ hi,
                        unsigned short* __restrict__ lo, int n8) {
  int i = blockIdx.x * blockDim.x + threadIdx.x;
  if (i >= n8) return;
  const float4* s = (const float4*)src;
  float4 f0 = s[i * 2], f1 = s[i * 2 + 1];
  uint4 h, l;
  split8(f0, f1, h, l);
  ((uint4*)hi)[i] = h;
  ((uint4*)lo)[i] = l;
}

// ------------------------------------------------------------------
// biasT[h][j][r] = attn_biases[h, bias_idxs[r, j]] * LOG2E   (fp32, as round 2)
// ------------------------------------------------------------------
__global__ void make_biasT(const float* __restrict__ ab, const int* __restrict__ idxs,
                           float* __restrict__ biasT, int n_off) {
  const int total = NH * NTOK * NTOKH;
  for (int idx = blockIdx.x * blockDim.x + threadIdx.x; idx < total;
       idx += gridDim.x * blockDim.x) {
    int r = idx % NTOKH;
    int j = (idx / NTOKH) % NTOK;
    int h = idx / (NTOKH * NTOK);
    biasT[idx] = ab[(size_t)h * n_off + idxs[r * NTOK + j]] * LOG2E;
  }
}

// ------------------------------------------------------------------
// MFMA GEMM, 3-way bf16 split: C[m,n] = sum_k A[m,k]*B[n,k]
// A fp32 (split on the fly), B pre-split bf16 hi/lo.
// 128x128 tile, BK=32, 4 waves (2x2), 4x4 16x16x32 frags per wave.
// ------------------------------------------------------------------
template <int OUT_BF16, int GATHER>
__global__ __launch_bounds__(256)
void gemm_mfma(const float* __restrict__ Af,
               const unsigned short* __restrict__ BhG, const unsigned short* __restrict__ BlG,
               float* __restrict__ Cf, unsigned short* __restrict__ Cb,
               int M, int N, int K) {
  __shared__ unsigned short Ah[128][40], Al[128][40], Bh[128][40], Bl[128][40];
  const int t = threadIdx.x;
  const int m0 = blockIdx.x * 128, n0 = blockIdx.y * 128;
  const int sr = t >> 1, sc = (t & 1) * 16;  // staging: row, col-offset
  int arow = m0 + sr;
  if (GATHER) {
    int bb = arow / NTOKH, r = arow - bb * NTOKH;
    int i = r / RESH, j = r - i * RESH;
    arow = bb * NTOK + i * (2 * RESF) + j * 2;
  }
  const int brow = n0 + sr;

  uint4 sAh0, sAh1, sAl0, sAl1, sBh0, sBh1, sBl0, sBl1;

  auto LOADSTAGE = [&](int k0) {
    const float* ap = Af + (size_t)arow * K + k0 + sc;
    float4 a0 = *(const float4*)ap;
    float4 a1 = *(const float4*)(ap + 4);
    float4 a2 = *(const float4*)(ap + 8);
    float4 a3 = *(const float4*)(ap + 12);
    split8(a0, a1, sAh0, sAl0);
    split8(a2, a3, sAh1, sAl1);
    const size_t ib = (size_t)brow * K + k0 + sc;
    sBh0 = *(const uint4*)&BhG[ib];
    sBh1 = *(const uint4*)&BhG[ib + 8];
    sBl0 = *(const uint4*)&BlG[ib];
    sBl1 = *(const uint4*)&BlG[ib + 8];
  };
  auto WRITESTAGE = [&]() {
    *(uint4*)&Ah[sr][sc] = sAh0;  *(uint4*)&Ah[sr][sc + 8] = sAh1;
    *(uint4*)&Al[sr][sc] = sAl0;  *(uint4*)&Al[sr][sc + 8] = sAl1;
    *(uint4*)&Bh[sr][sc] = sBh0;  *(uint4*)&Bh[sr][sc + 8] = sBh1;
    *(uint4*)&Bl[sr][sc] = sBl0;  *(uint4*)&Bl[sr][sc + 8] = sBl1;
  };

  const int wave = t >> 6, lane = t & 63;
  const int wm64 = (wave >> 1) * 64, wn64 = (wave & 1) * 64;
  const int fr = lane & 15, fg8 = (lane >> 4) * 8;

  f32x4 acc[4][4];
#pragma unroll
  for (int i = 0; i < 4; ++i)
#pragma unroll
    for (int j = 0; j < 4; ++j) acc[i][j] = f32x4{0.f, 0.f, 0.f, 0.f};

  const int nK = K / 32;
  LOADSTAGE(0);
  for (int kt = 0; kt < nK; ++kt) {
    __syncthreads();          // previous tile's frag reads complete
    WRITESTAGE();
    __syncthreads();          // tile ready
    if (kt + 1 < nK) LOADSTAGE((kt + 1) * 32);  // prefetch next (regs only)
    bf16x8 ah[4], al[4];
#pragma unroll
    for (int fm = 0; fm < 4; ++fm) {
      ah[fm] = *(const bf16x8*)&Ah[wm64 + fm * 16 + fr][fg8];
      al[fm] = *(const bf16x8*)&Al[wm64 + fm * 16 + fr][fg8];
    }
#pragma unroll
    for (int fn = 0; fn < 4; ++fn) {
      bf16x8 bh = *(const bf16x8*)&Bh[wn64 + fn * 16 + fr][fg8];
      bf16x8 bl = *(const bf16x8*)&Bl[wn64 + fn * 16 + fr][fg8];
#pragma unroll
      for (int fm = 0; fm < 4; ++fm) {
        acc[fm][fn] = __builtin_amdgcn_mfma_f32_16x16x32_bf16(ah[fm], bh, acc[fm][fn], 0, 0, 0);
        acc[fm][fn] = __builtin_amdgcn_mfma_f32_16x16x32_bf16(al[fm], bh, acc[fm][fn], 0, 0, 0);
        acc[fm][fn] = __builtin_amdgcn_mfma_f32_16x16x32_bf16(ah[fm], bl, acc[fm][fn], 0, 0, 0);
      }
    }
  }

  // epilogue: D col=lane&15, row=(lane>>4)*4+reg (m89-verified)
#pragma unroll
  for (int fm = 0; fm < 4; ++fm) {
    const int row0 = m0 + wm64 + fm * 16 + (lane >> 4) * 4;
#pragma unroll
    for (int fn = 0; fn < 4; ++fn) {
      const int col = n0 + wn64 + fn * 16 + fr;
#pragma unroll
      for (int j = 0; j < 4; ++j) {
        const size_t off = (size_t)(row0 + j) * N + col;
        if (OUT_BF16) Cb[off] = f2bf(acc[fm][fn][j]);
        else Cf[off] = acc[fm][fn][j];
      }
    }
  }
}

// ------------------------------------------------------------------
// fp32 GEMM (round-2 verified), used for the proj GEMM only.
// C[m,n] = sum_k A[m,k] * B[n,k]
// ------------------------------------------------------------------
__global__ __launch_bounds__(256)
void gemm_nt(const float* __restrict__ A, const float* __restrict__ Bm,
             float* __restrict__ C, int M, int N, int K) {
  __shared__ float As[2][16][132];
  __shared__ float Bs[2][16][132];
  const int t = threadIdx.x;
  const int tx = t & 15, ty = t >> 4;
  const int m0 = blockIdx.x * 128, n0 = blockIdx.y * 128;
  const int lr = t >> 2, lk = (t & 3) * 4;

  const float* Apa = A + (size_t)(m0 + lr) * K + lk;
  const float* Apb = A + (size_t)(m0 + lr + 64) * K + lk;
  const float* Bpa = Bm + (size_t)(n0 + lr) * K + lk;
  const float* Bpb = Bm + (size_t)(n0 + lr + 64) * K + lk;

  float4 pa0, pa1, pb0, pb1;
  auto loadAB = [&](int k0) {
    pa0 = *(const float4*)(Apa + k0);
    pa1 = *(const float4*)(Apb + k0);
    pb0 = *(const float4*)(Bpa + k0);
    pb1 = *(const float4*)(Bpb + k0);
  };
  auto storeAB = [&](int buf) {
    As[buf][lk + 0][lr] = pa0.x; As[buf][lk + 1][lr] = pa0.y;
    As[buf][lk + 2][lr] = pa0.z; As[buf][lk + 3][lr] = pa0.w;
    As[buf][lk + 0][lr + 64] = pa1.x; As[buf][lk + 1][lr + 64] = pa1.y;
    As[buf][lk + 2][lr + 64] = pa1.z; As[buf][lk + 3][lr + 64] = pa1.w;
    Bs[buf][lk + 0][lr] = pb0.x; Bs[buf][lk + 1][lr] = pb0.y;
    Bs[buf][lk + 2][lr] = pb0.z; Bs[buf][lk + 3][lr] = pb0.w;
    Bs[buf][lk + 0][lr + 64] = pb1.x; Bs[buf][lk + 1][lr + 64] = pb1.y;
    Bs[buf][lk + 2][lr + 64] = pb1.z; Bs[buf][lk + 3][lr + 64] = pb1.w;
  };

  float acc[8][8];
#pragma unroll
  for (int i = 0; i < 8; ++i)
#pragma unroll
    for (int j = 0; j < 8; ++j) acc[i][j] = 0.f;

  loadAB(0);
  storeAB(0);
  __syncthreads();

  const int nt = K / 16;
  for (int tt = 0; tt < nt; ++tt) {
    const int buf = tt & 1;
    if (tt + 1 < nt) loadAB((tt + 1) * 16);
#pragma unroll
    for (int kk = 0; kk < 16; ++kk) {
      float a[8], b[8];
      *(float4*)&a[0] = *(const float4*)&As[buf][kk][ty * 8];
      *(float4*)&a[4] = *(const float4*)&As[buf][kk][ty * 8 + 4];
      *(float4*)&b[0] = *(const float4*)&Bs[buf][kk][tx * 8];
      *(float4*)&b[4] = *(const float4*)&Bs[buf][kk][tx * 8 + 4];
#pragma unroll
      for (int i = 0; i < 8; ++i)
#pragma unroll
        for (int j = 0; j < 8; ++j) acc[i][j] = fmaf(a[i], b[j], acc[i][j]);
    }
    if (tt + 1 < nt) storeAB(buf ^ 1);
    __syncthreads();
  }

#pragma unroll
  for (int i = 0; i < 8; ++i) {
    const int m = m0 + ty * 8 + i;
    float4 c0 = make_float4(acc[i][0], acc[i][1], acc[i][2], acc[i][3]);
    float4 c1 = make_float4(acc[i][4], acc[i][5], acc[i][6], acc[i][7]);
    *(float4*)&C[(size_t)m * N + n0 + tx * 8] = c0;
    *(float4*)&C[(size_t)m * N + n0 + tx * 8 + 4] = c1;
  }
}

// ------------------------------------------------------------------
// Column stats (two stage), round-2 verified.
// ------------------------------------------------------------------
template <typename TY>
__global__ void col_stats_partial(const TY* __restrict__ Y, double2* __restrict__ part,
                                  int M, int NC) {
  const int col = blockIdx.x * 64 + (threadIdx.x & 63);
  const int rs = threadIdx.x >> 6;
  const int chunk = blockIdx.y;
  const int rpc = (M + 63) / 64;
  const int r0 = chunk * rpc;
  const int r1 = (r0 + rpc < M) ? (r0 + rpc) : M;
  double s = 0.0, s2 = 0.0;
  for (int r = r0 + rs; r < r1; r += 4) {
    float v;
    if constexpr (std::is_same<TY, float>::value) v = Y[(size_t)r * NC + col];
    else v = bf2f(Y[(size_t)r * NC + col]);
    s += (double)v;
    s2 += (double)v * (double)v;
  }
  __shared__ double sh[2][4][64];
  sh[0][rs][threadIdx.x & 63] = s;
  sh[1][rs][threadIdx.x & 63] = s2;
  __syncthreads();
  if (threadIdx.x < 64) {
    int c = threadIdx.x;
    double ts = sh[0][0][c] + sh[0][1][c] + sh[0][2][c] + sh[0][3][c];
    double t2 = sh[1][0][c] + sh[1][1][c] + sh[1][2][c] + sh[1][3][c];
    part[(size_t)chunk * NC + col] = make_double2(ts, t2);
  }
}

__global__ void col_stats_finalize(const double2* __restrict__ part,
                                   const float* __restrict__ g, const float* __restrict__ bb,
                                   float* __restrict__ Aout, float* __restrict__ Cout,
                                   int NC, int M, float mul) {
  const int col = blockIdx.x * blockDim.x + threadIdx.x;
  if (col >= NC) return;
  double s = 0.0, s2 = 0.0;
  for (int ch = 0; ch < 64; ++ch) {
    double2 p = part[(size_t)ch * NC + col];
    s += p.x;
    s2 += p.y;
  }
  double mean = s / (double)M;
  double var = s2 / (double)M - mean * mean;
  double A0 = (double)g[col] / sqrt(var + (double)BN_EPS);
  Aout[col] = (float)(A0 * (double)mul);
  Cout[col] = (float)(((double)bb[col] - mean * A0) * (double)mul);
}

// ------------------------------------------------------------------
// Flash attention per (b,h), round-2 verified (fp32 bias, fp32 out).
// ------------------------------------------------------------------
#define TJ 112
__device__ inline float hswish(float x) {
  float r = fminf(fmaxf(x + 3.f, 0.f), 6.f);
  return x * r * (1.f / 6.f);
}

__global__ __launch_bounds__(256)
void attn_kernel(const unsigned short* __restrict__ Ykv, const float* __restrict__ Yq,
                 const float* __restrict__ biasT,
                 const float* __restrict__ Akv, const float* __restrict__ Ckv,
                 const float* __restrict__ Aq, const float* __restrict__ Cq,
                 float* __restrict__ Out) {
  const int b = blockIdx.x, h = blockIdx.y;
  const int t = threadIdx.x;
  __shared__ float ks[TJ][KDIM];
  __shared__ float vs[TJ][VDIM];
  __shared__ float akv_s[96], ckv_s[96];

  if (t < 96) {
    akv_s[t] = Akv[h * 96 + t];
    ckv_s[t] = Ckv[h * 96 + t];
  }

  float q[KDIM];
  if (t < NTOKH) {
    const float* qp = &Yq[((size_t)b * NTOKH + t) * NQC + h * KDIM];
#pragma unroll
    for (int d = 0; d < KDIM; d += 4) {
      float4 v4 = *(const float4*)&qp[d];
      q[d + 0] = v4.x * Aq[h * KDIM + d + 0] + Cq[h * KDIM + d + 0];
      q[d + 1] = v4.y * Aq[h * KDIM + d + 1] + Cq[h * KDIM + d + 1];
      q[d + 2] = v4.z * Aq[h * KDIM + d + 2] + Cq[h * KDIM + d + 2];
      q[d + 3] = v4.w * Aq[h * KDIM + d + 3] + Cq[h * KDIM + d + 3];
    }
  }

  float m_run = -1e30f, l_run = 0.f;
  float acc[VDIM];
#pragma unroll
  for (int d = 0; d < VDIM; ++d) acc[d] = 0.f;

  for (int tile = 0; tile < NTOK / TJ; ++tile) {
    const int n0 = tile * TJ;
    __syncthreads();
    for (int idx = t; idx < TJ * 24; idx += 256) {
      int row = idx / 24;
      int c4 = (idx % 24) * 4;
      ushort4 u4 = *(const ushort4*)&Ykv[((size_t)(b * NTOK + n0 + row)) * NKV + h * 96 + c4];
      float vv[4] = {bf2f(u4.x), bf2f(u4.y), bf2f(u4.z), bf2f(u4.w)};
#pragma unroll
      for (int i = 0; i < 4; ++i) {
        int ch = c4 + i;
        float nv = vv[i] * akv_s[ch] + ckv_s[ch];
        if (ch < KDIM) ks[row][ch] = nv;
        else vs[row][ch - KDIM] = nv;
      }
    }
    __syncthreads();

    float bcur = 0.f;
    if (t < NTOKH) bcur = biasT[((size_t)h * NTOK + n0) * NTOKH + t];
    for (int j = 0; j < TJ; ++j) {
      float bnext = 0.f;
      if (t < NTOKH && j + 1 < TJ)
        bnext = biasT[((size_t)h * NTOK + n0 + j + 1) * NTOKH + t];
      if (t < NTOKH) {
        float s = bcur;
#pragma unroll
        for (int kk = 0; kk < KDIM; kk += 4) {
          float4 k4 = *(const float4*)&ks[j][kk];
          s = fmaf(q[kk + 0], k4.x, s);
          s = fmaf(q[kk + 1], k4.y, s);
          s = fmaf(q[kk + 2], k4.z, s);
          s = fmaf(q[kk + 3], k4.w, s);
        }
        float p;
        if (s > m_run + 8.f) {  // defer-max rescale (rare)
          float corr = __builtin_exp2f(m_run - s);
          l_run *= corr;
#pragma unroll
          for (int d = 0; d < VDIM; ++d) acc[d] *= corr;
          m_run = s;
          p = 1.f;
        } else {
          p = __builtin_exp2f(s - m_run);
        }
        l_run += p;
#pragma unroll
        for (int d = 0; d < VDIM; d += 4) {
          float4 v4 = *(const float4*)&vs[j][d];
          acc[d + 0] = fmaf(p, v4.x, acc[d + 0]);
          acc[d + 1] = fmaf(p, v4.y, acc[d + 1]);
          acc[d + 2] = fmaf(p, v4.z, acc[d + 2]);
          acc[d + 3] = fmaf(p, v4.w, acc[d + 3]);
        }
      }
      bcur = bnext;
    }
  }

  if (t < NTOKH) {
    float inv = 1.f / l_run;
    float* op = &Out[((size_t)b * NTOKH + t) * DH + h * VDIM];
#pragma unroll
    for (int d = 0; d < VDIM; d += 4) {
      float4 o;
      o.x = hswish(acc[d + 0] * inv);
      o.y = hswish(acc[d + 1] * inv);
      o.z = hswish(acc[d + 2] * inv);
      o.w = hswish(acc[d + 3] * inv);
      *(float4*)&op[d] = o;
    }
  }
}

// ------------------------------------------------------------------
__global__ void norm_out(const float* __restrict__ Yp, const float* __restrict__ Ap,
                         const float* __restrict__ Cp, float* __restrict__ out) {
  const int total = MQ * (NP / 4);
  for (int idx = blockIdx.x * blockDim.x + threadIdx.x; idx < total;
       idx += gridDim.x * blockDim.x) {
    int c4 = (idx % (NP / 4)) * 4;
    float4 y = ((const float4*)Yp)[idx];
    float4 o;
    o.x = y.x * Ap[c4 + 0] + Cp[c4 + 0];
    o.y = y.y * Ap[c4 + 1] + Cp[c4 + 1];
    o.z = y.z * Ap[c4 + 2] + Cp[c4 + 2];
    o.w = y.w * Ap[c4 + 3] + Cp[c4 + 3];
    ((float4*)out)[idx] = o;
  }
}

// ------------------------------------------------------------------
extern "C" void kernel_launch(void* const* d_in, const int* in_sizes, int n_in,
                              void* d_out, int out_size, void* d_ws, size_t ws_size,
                              hipStream_t stream) {
  const float* x      = (const float*)d_in[0];
  const float* W_kv   = (const float*)d_in[1];
  const float* g_kv   = (const float*)d_in[2];
  const float* b_kv   = (const float*)d_in[3];
  const float* W_q    = (const float*)d_in[4];
  const float* g_q    = (const float*)d_in[5];
  const float* b_q    = (const float*)d_in[6];
  const float* W_proj = (const float*)d_in[7];
  const float* g_proj = (const float*)d_in[8];
  const float* b_proj = (const float*)d_in[9];
  const float* attn_b = (const float*)d_in[10];
  const int* bias_idxs = (const int*)d_in[11];
  const int n_off = in_sizes[10] / NH;

  // ---- workspace layout: EXACTLY round-2's proven 242.64 MB bf16 layout ----
  float* ws = (float*)d_ws;
  size_t off = 0;
  unsigned short* Ykv = (unsigned short*)(ws + off);  off += (size_t)MKV * NKV / 2;
  float* Yq = ws + off;                               off += (size_t)MQ * NQC;
  float* Out = ws + off;                              off += (size_t)MQ * DH;
  float* BiasT = ws + off;                            off += (size_t)NH * NTOK * NTOKH;
  double2* part = (double2*)(ws + off);               off += (size_t)64 * NKV * 4;
  float* AC = ws + off;                               off += 2 * NKV + 2 * NQC + 2 * NP;

  float* Akv = AC;            float* Ckv = AC + NKV;
  float* Aq = AC + 2 * NKV;   float* Cq = AC + 2 * NKV + NQC;
  float* Ap = AC + 2 * NKV + 2 * NQC;
  float* Cp = AC + 2 * NKV + 2 * NQC + NP;

  // W splits aliased into Out (Out is only written by attn, AFTER both
  // MFMA GEMMs have fully consumed the splits; stream-ordered => safe).
  unsigned short* WkvH = (unsigned short*)Out;             // 786,432 ush
  unsigned short* WkvL = WkvH + (size_t)NKV * CIN;         // 786,432
  unsigned short* WqH  = WkvL + (size_t)NKV * CIN;         // 262,144
  unsigned short* WqL  = WqH + (size_t)NQC * CIN;          // 262,144  (total 4MB << 51MB)

  // Yp aliases Ykv region (dead after attention)
  float* Yp = ws;

  const float qmul = 0.17677669529663687f * LOG2E;  // KD^-0.5 * log2(e)

  make_biasT<<<dim3(2048), dim3(256), 0, stream>>>(attn_b, bias_idxs, BiasT, n_off);
  split_w<<<dim3((NKV * CIN / 8 + 255) / 256), dim3(256), 0, stream>>>(W_kv, WkvH, WkvL, NKV * CIN / 8);
  split_w<<<dim3((NQC * CIN / 8 + 255) / 256), dim3(256), 0, stream>>>(W_q, WqH, WqL, NQC * CIN / 8);

  gemm_mfma<1, 0><<<dim3(MKV / 128, NKV / 128), dim3(256), 0, stream>>>(
      x, WkvH, WkvL, nullptr, Ykv, MKV, NKV, CIN);
  gemm_mfma<0, 1><<<dim3(MQ / 128, NQC / 128), dim3(256), 0, stream>>>(
      x, WqH, WqL, Yq, nullptr, MQ, NQC, CIN);

  col_stats_partial<unsigned short><<<dim3(NKV / 64, 64), dim3(256), 0, stream>>>(Ykv, part, MKV, NKV);
  col_stats_finalize<<<dim3(NKV / 256), dim3(256), 0, stream>>>(part, g_kv, b_kv, Akv, Ckv, NKV, MKV, 1.0f);
  col_stats_partial<float><<<dim3(NQC / 64, 64), dim3(256), 0, stream>>>(Yq, part, MQ, NQC);
  col_stats_finalize<<<dim3(NQC / 256), dim3(256), 0, stream>>>(part, g_q, b_q, Aq, Cq, NQC, MQ, qmul);

  attn_kernel<<<dim3(NB, NH), dim3(256), 0, stream>>>(Ykv, Yq, BiasT, Akv, Ckv, Aq, Cq, Out);

  gemm_nt<<<dim3(MQ / 128, NP / 128), dim3(256), 0, stream>>>(Out, W_proj, Yp, MQ, NP, DH);
  col_stats_partial<float><<<dim3(NP / 64, 64), dim3(256), 0, stream>>>(Yp, part, MQ, NP);
  col_stats_finalize<<<dim3(NP / 256), dim3(256), 0, stream>>>(part, g_proj, b_proj, Ap, Cp, NP, MQ, 1.0f);

  norm_out<<<dim3(2048), dim3(256), 0, stream>>>(Yp, Ap, Cp, (float*)d_out);
}

// Round 6
// 1400.113 us; speedup vs baseline: 2.4618x; 1.6089x over previous
//
#include <hip/hip_runtime.h>
#include <math.h>
#include <type_traits>

#define RESF 28
#define RESH 14
#define NH 16
#define KDIM 32
#define VDIM 64
#define CIN 512
#define NKV 1536   // NH*(KDIM+VDIM)
#define NQC 512    // NH*KDIM
#define NP 768
#define DH 1024    // NH*VDIM
#define NTOK 784
#define NTOKH 196
#define NB 64
#define MKV (NB*NTOK)    // 50176
#define MQ  (NB*NTOKH)   // 12544
#define BN_EPS 1e-5f
#define LOG2E 1.44269504088896f

typedef __attribute__((ext_vector_type(8))) short bf16x8;
typedef __attribute__((ext_vector_type(4))) float f32x4;

// ---------------- bf16 helpers (raw ushort bits) ----------------
__device__ inline unsigned short f2bf(float f) {  // RNE
  unsigned int u = __float_as_uint(f);
  unsigned int r = u + 0x7fffu + ((u >> 16) & 1u);
  return (unsigned short)(r >> 16);
}
__device__ inline float bf2f(unsigned short h) {
  return __uint_as_float(((unsigned int)h) << 16);
}

// split 8 floats -> packed bf16 hi (RNE) and lo (truncated residual)
__device__ inline void split8(const float4 f0, const float4 f1, uint4& hi, uint4& lo) {
  float f[8] = {f0.x, f0.y, f0.z, f0.w, f1.x, f1.y, f1.z, f1.w};
  unsigned hh[8], ll[8];
#pragma unroll
  for (int i = 0; i < 8; ++i) {
    unsigned u = __float_as_uint(f[i]);
    unsigned r = u + 0x7fffu + ((u >> 16) & 1u);
    unsigned h = r >> 16;
    hh[i] = h;
    float rf = f[i] - __uint_as_float(h << 16);
    ll[i] = __float_as_uint(rf) >> 16;
  }
  hi = make_uint4(hh[0] | (hh[1] << 16), hh[2] | (hh[3] << 16),
                  hh[4] | (hh[5] << 16), hh[6] | (hh[7] << 16));
  lo = make_uint4(ll[0] | (ll[1] << 16), ll[2] | (ll[3] << 16),
                  ll[4] | (ll[5] << 16), ll[6] | (ll[7] << 16));
}

// ------------------------------------------------------------------
__global__ void split_w(const float* __restrict__ src, unsigned short* __restrict__ hi,
                        unsigned short* __restrict__ lo, int n8) {
  int i = blockIdx.x * blockDim.x + threadIdx.x;
  if (i >= n8) return;
  const float4* s = (const float4*)src;
  float4 f0 = s[i * 2], f1 = s[i * 2 + 1];
  uint4 h, l;
  split8(f0, f1, h, l);
  ((uint4*)hi)[i] = h;
  ((uint4*)lo)[i] = l;
}

// ------------------------------------------------------------------
// Bias in MFMA fragment layout (bf16):
// BiasF[(((h*49 + kt)*13 + qt)*64 + lane)*4 + j] =
//   bias(q = qt*16 + (lane>>4)*4 + j, key = kt*16 + (lane&15)) * LOG2E
// ------------------------------------------------------------------
__global__ void make_biasF(const float* __restrict__ ab, const int* __restrict__ idxs,
                           unsigned short* __restrict__ biasF, int n_off) {
  const int total = NH * 49 * 13 * 64 * 4;  // 2,609,152
  for (int e = blockIdx.x * blockDim.x + threadIdx.x; e < total;
       e += gridDim.x * blockDim.x) {
    int j = e & 3;
    int lane = (e >> 2) & 63;
    int rest = e >> 8;
    int qt = rest % 13;
    int rest2 = rest / 13;
    int kt = rest2 % 49;
    int h = rest2 / 49;
    int q = qt * 16 + (lane >> 4) * 4 + j;
    int key = kt * 16 + (lane & 15);
    float v = 0.f;
    if (q < NTOKH) v = ab[(size_t)h * n_off + idxs[q * NTOK + key]] * LOG2E;
    biasF[e] = f2bf(v);
  }
}

// ------------------------------------------------------------------
// MFMA GEMM, 3-way bf16 split (round-4 verified).
// ------------------------------------------------------------------
template <int OUT_BF16, int GATHER>
__global__ __launch_bounds__(256)
void gemm_mfma(const float* __restrict__ Af,
               const unsigned short* __restrict__ BhG, const unsigned short* __restrict__ BlG,
               float* __restrict__ Cf, unsigned short* __restrict__ Cb,
               int M, int N, int K) {
  __shared__ unsigned short Ah[128][40], Al[128][40], Bh[128][40], Bl[128][40];
  const int t = threadIdx.x;
  const int m0 = blockIdx.x * 128, n0 = blockIdx.y * 128;
  const int sr = t >> 1, sc = (t & 1) * 16;
  int arow = m0 + sr;
  if (GATHER) {
    int bb = arow / NTOKH, r = arow - bb * NTOKH;
    int i = r / RESH, j = r - i * RESH;
    arow = bb * NTOK + i * (2 * RESF) + j * 2;
  }
  const int brow = n0 + sr;

  uint4 sAh0, sAh1, sAl0, sAl1, sBh0, sBh1, sBl0, sBl1;

  auto LOADSTAGE = [&](int k0) {
    const float* ap = Af + (size_t)arow * K + k0 + sc;
    float4 a0 = *(const float4*)ap;
    float4 a1 = *(const float4*)(ap + 4);
    float4 a2 = *(const float4*)(ap + 8);
    float4 a3 = *(const float4*)(ap + 12);
    split8(a0, a1, sAh0, sAl0);
    split8(a2, a3, sAh1, sAl1);
    const size_t ib = (size_t)brow * K + k0 + sc;
    sBh0 = *(const uint4*)&BhG[ib];
    sBh1 = *(const uint4*)&BhG[ib + 8];
    sBl0 = *(const uint4*)&BlG[ib];
    sBl1 = *(const uint4*)&BlG[ib + 8];
  };
  auto WRITESTAGE = [&]() {
    *(uint4*)&Ah[sr][sc] = sAh0;  *(uint4*)&Ah[sr][sc + 8] = sAh1;
    *(uint4*)&Al[sr][sc] = sAl0;  *(uint4*)&Al[sr][sc + 8] = sAl1;
    *(uint4*)&Bh[sr][sc] = sBh0;  *(uint4*)&Bh[sr][sc + 8] = sBh1;
    *(uint4*)&Bl[sr][sc] = sBl0;  *(uint4*)&Bl[sr][sc + 8] = sBl1;
  };

  const int wave = t >> 6, lane = t & 63;
  const int wm64 = (wave >> 1) * 64, wn64 = (wave & 1) * 64;
  const int fr = lane & 15, fg8 = (lane >> 4) * 8;

  f32x4 acc[4][4];
#pragma unroll
  for (int i = 0; i < 4; ++i)
#pragma unroll
    for (int j = 0; j < 4; ++j) acc[i][j] = f32x4{0.f, 0.f, 0.f, 0.f};

  const int nK = K / 32;
  LOADSTAGE(0);
  for (int kt = 0; kt < nK; ++kt) {
    __syncthreads();
    WRITESTAGE();
    __syncthreads();
    if (kt + 1 < nK) LOADSTAGE((kt + 1) * 32);
    bf16x8 ah[4], al[4];
#pragma unroll
    for (int fm = 0; fm < 4; ++fm) {
      ah[fm] = *(const bf16x8*)&Ah[wm64 + fm * 16 + fr][fg8];
      al[fm] = *(const bf16x8*)&Al[wm64 + fm * 16 + fr][fg8];
    }
#pragma unroll
    for (int fn = 0; fn < 4; ++fn) {
      bf16x8 bh = *(const bf16x8*)&Bh[wn64 + fn * 16 + fr][fg8];
      bf16x8 bl = *(const bf16x8*)&Bl[wn64 + fn * 16 + fr][fg8];
#pragma unroll
      for (int fm = 0; fm < 4; ++fm) {
        acc[fm][fn] = __builtin_amdgcn_mfma_f32_16x16x32_bf16(ah[fm], bh, acc[fm][fn], 0, 0, 0);
        acc[fm][fn] = __builtin_amdgcn_mfma_f32_16x16x32_bf16(al[fm], bh, acc[fm][fn], 0, 0, 0);
        acc[fm][fn] = __builtin_amdgcn_mfma_f32_16x16x32_bf16(ah[fm], bl, acc[fm][fn], 0, 0, 0);
      }
    }
  }

#pragma unroll
  for (int fm = 0; fm < 4; ++fm) {
    const int row0 = m0 + wm64 + fm * 16 + (lane >> 4) * 4;
#pragma unroll
    for (int fn = 0; fn < 4; ++fn) {
      const int col = n0 + wn64 + fn * 16 + fr;
#pragma unroll
      for (int j = 0; j < 4; ++j) {
        const size_t off = (size_t)(row0 + j) * N + col;
        if (OUT_BF16) Cb[off] = f2bf(acc[fm][fn][j]);
        else Cf[off] = acc[fm][fn][j];
      }
    }
  }
}

// ------------------------------------------------------------------
// fp32 GEMM (round-2 verified), proj GEMM only.
// ------------------------------------------------------------------
__global__ __launch_bounds__(256)
void gemm_nt(const float* __restrict__ A, const float* __restrict__ Bm,
             float* __restrict__ C, int M, int N, int K) {
  __shared__ float As[2][16][132];
  __shared__ float Bs[2][16][132];
  const int t = threadIdx.x;
  const int tx = t & 15, ty = t >> 4;
  const int m0 = blockIdx.x * 128, n0 = blockIdx.y * 128;
  const int lr = t >> 2, lk = (t & 3) * 4;

  const float* Apa = A + (size_t)(m0 + lr) * K + lk;
  const float* Apb = A + (size_t)(m0 + lr + 64) * K + lk;
  const float* Bpa = Bm + (size_t)(n0 + lr) * K + lk;
  const float* Bpb = Bm + (size_t)(n0 + lr + 64) * K + lk;

  float4 pa0, pa1, pb0, pb1;
  auto loadAB = [&](int k0) {
    pa0 = *(const float4*)(Apa + k0);
    pa1 = *(const float4*)(Apb + k0);
    pb0 = *(const float4*)(Bpa + k0);
    pb1 = *(const float4*)(Bpb + k0);
  };
  auto storeAB = [&](int buf) {
    As[buf][lk + 0][lr] = pa0.x; As[buf][lk + 1][lr] = pa0.y;
    As[buf][lk + 2][lr] = pa0.z; As[buf][lk + 3][lr] = pa0.w;
    As[buf][lk + 0][lr + 64] = pa1.x; As[buf][lk + 1][lr + 64] = pa1.y;
    As[buf][lk + 2][lr + 64] = pa1.z; As[buf][lk + 3][lr + 64] = pa1.w;
    Bs[buf][lk + 0][lr] = pb0.x; Bs[buf][lk + 1][lr] = pb0.y;
    Bs[buf][lk + 2][lr] = pb0.z; Bs[buf][lk + 3][lr] = pb0.w;
    Bs[buf][lk + 0][lr + 64] = pb1.x; Bs[buf][lk + 1][lr + 64] = pb1.y;
    Bs[buf][lk + 2][lr + 64] = pb1.z; Bs[buf][lk + 3][lr + 64] = pb1.w;
  };

  float acc[8][8];
#pragma unroll
  for (int i = 0; i < 8; ++i)
#pragma unroll
    for (int j = 0; j < 8; ++j) acc[i][j] = 0.f;

  loadAB(0);
  storeAB(0);
  __syncthreads();

  const int nt = K / 16;
  for (int tt = 0; tt < nt; ++tt) {
    const int buf = tt & 1;
    if (tt + 1 < nt) loadAB((tt + 1) * 16);
#pragma unroll
    for (int kk = 0; kk < 16; ++kk) {
      float a[8], b[8];
      *(float4*)&a[0] = *(const float4*)&As[buf][kk][ty * 8];
      *(float4*)&a[4] = *(const float4*)&As[buf][kk][ty * 8 + 4];
      *(float4*)&b[0] = *(const float4*)&Bs[buf][kk][tx * 8];
      *(float4*)&b[4] = *(const float4*)&Bs[buf][kk][tx * 8 + 4];
#pragma unroll
      for (int i = 0; i < 8; ++i)
#pragma unroll
        for (int j = 0; j < 8; ++j) acc[i][j] = fmaf(a[i], b[j], acc[i][j]);
    }
    if (tt + 1 < nt) storeAB(buf ^ 1);
    __syncthreads();
  }

#pragma unroll
  for (int i = 0; i < 8; ++i) {
    const int m = m0 + ty * 8 + i;
    float4 c0 = make_float4(acc[i][0], acc[i][1], acc[i][2], acc[i][3]);
    float4 c1 = make_float4(acc[i][4], acc[i][5], acc[i][6], acc[i][7]);
    *(float4*)&C[(size_t)m * N + n0 + tx * 8] = c0;
    *(float4*)&C[(size_t)m * N + n0 + tx * 8 + 4] = c1;
  }
}

// ------------------------------------------------------------------
// Column stats (two stage), round-2 verified.
// ------------------------------------------------------------------
template <typename TY>
__global__ void col_stats_partial(const TY* __restrict__ Y, double2* __restrict__ part,
                                  int M, int NC) {
  const int col = blockIdx.x * 64 + (threadIdx.x & 63);
  const int rs = threadIdx.x >> 6;
  const int chunk = blockIdx.y;
  const int rpc = (M + 63) / 64;
  const int r0 = chunk * rpc;
  const int r1 = (r0 + rpc < M) ? (r0 + rpc) : M;
  double s = 0.0, s2 = 0.0;
  for (int r = r0 + rs; r < r1; r += 4) {
    float v;
    if constexpr (std::is_same<TY, float>::value) v = Y[(size_t)r * NC + col];
    else v = bf2f(Y[(size_t)r * NC + col]);
    s += (double)v;
    s2 += (double)v * (double)v;
  }
  __shared__ double sh[2][4][64];
  sh[0][rs][threadIdx.x & 63] = s;
  sh[1][rs][threadIdx.x & 63] = s2;
  __syncthreads();
  if (threadIdx.x < 64) {
    int c = threadIdx.x;
    double ts = sh[0][0][c] + sh[0][1][c] + sh[0][2][c] + sh[0][3][c];
    double t2 = sh[1][0][c] + sh[1][1][c] + sh[1][2][c] + sh[1][3][c];
    part[(size_t)chunk * NC + col] = make_double2(ts, t2);
  }
}

__global__ void col_stats_finalize(const double2* __restrict__ part,
                                   const float* __restrict__ g, const float* __restrict__ bb,
                                   float* __restrict__ Aout, float* __restrict__ Cout,
                                   int NC, int M, float mul) {
  const int col = blockIdx.x * blockDim.x + threadIdx.x;
  if (col >= NC) return;
  double s = 0.0, s2 = 0.0;
  for (int ch = 0; ch < 64; ++ch) {
    double2 p = part[(size_t)ch * NC + col];
    s += p.x;
    s2 += p.y;
  }
  double mean = s / (double)M;
  double var = s2 / (double)M - mean * mean;
  double A0 = (double)g[col] / sqrt(var + (double)BN_EPS);
  Aout[col] = (float)(A0 * (double)mul);
  Cout[col] = (float)(((double)bb[col] - mean * A0) * (double)mul);
}

// ------------------------------------------------------------------
// MFMA flash attention. One block per (b,h), 4 waves.
// q-tiles of 16 rows: 13 tiles (208 rows, rows>=196 masked), split 4/3/3/3.
// K/V staged per 112-key outer tile; keys processed in 32-key groups
// (odd 16-tile handled via phantom scores = -1e30 => P=0).
// Scores in exp2 domain. Distributed l, defer-max(8), final shfl reduce.
// ------------------------------------------------------------------
__device__ inline float hswish(float x) {
  float r = fminf(fmaxf(x + 3.f, 0.f), 6.f);
  return x * r * (1.f / 6.f);
}

__global__ __launch_bounds__(256)
void attn_mfma(const unsigned short* __restrict__ Ykv, const float* __restrict__ Yq,
               const unsigned short* __restrict__ BiasF,
               const float* __restrict__ Akv, const float* __restrict__ Ckv,
               const float* __restrict__ Aq, const float* __restrict__ Cq,
               float* __restrict__ Out) {
  const int b = blockIdx.x, h = blockIdx.y;
  const int t = threadIdx.x;
  const int wave = t >> 6, lane = t & 63;
  const int c = lane & 15, g = lane >> 4;  // fragment col / k-group

  __shared__ unsigned short Kl[112][40];      // [key][kdim]
  __shared__ unsigned short Vt[64][136];      // [d][key] (transposed V)
  __shared__ unsigned short Pl[4][16][40];    // per-wave P transpose buffer
  __shared__ float akv_s[96], ckv_s[96];

  if (t < 96) {
    akv_s[t] = Akv[h * 96 + t];
    ckv_s[t] = Ckv[h * 96 + t];
  }
  // Zero Vt's tail columns: kt32=3 reads keys 96..127 but only 112 keys are
  // staged; uninitialized LDS bits could be NaN and 0*NaN = NaN in MFMA.
  for (int idx = t; idx < 64 * 24; idx += 256)
    Vt[idx / 24][112 + (idx % 24)] = 0;

  const int nt = (wave == 0) ? 4 : 3;  // q-tiles: wave + i*4

  // ---- Q fragments (A-operand): lane holds Q[q=c][kd=g*8+j] ----
  bf16x8 qf[4];
#pragma unroll
  for (int i = 0; i < 4; ++i) {
    if (i >= nt) break;
    const int tile = wave + i * 4;
    const int ql = tile * 16 + c;
    bf16x8 qv = {0, 0, 0, 0, 0, 0, 0, 0};
    if (ql < NTOKH) {
      const int c0 = h * KDIM + g * 8;
      const float* qp = &Yq[((size_t)b * NTOKH + ql) * NQC + c0];
      float4 a0 = *(const float4*)qp;
      float4 a1 = *(const float4*)(qp + 4);
      float v[8] = {a0.x, a0.y, a0.z, a0.w, a1.x, a1.y, a1.z, a1.w};
#pragma unroll
      for (int jj = 0; jj < 8; ++jj)
        qv[jj] = (short)f2bf(v[jj] * Aq[c0 + jj] + Cq[c0 + jj]);
    }
    qf[i] = qv;
  }

  f32x4 acc[4][4];
  float m_r[4][4], l_r[4][4];
#pragma unroll
  for (int i = 0; i < 4; ++i)
#pragma unroll
    for (int d = 0; d < 4; ++d) acc[i][d] = f32x4{0.f, 0.f, 0.f, 0.f};
#pragma unroll
  for (int i = 0; i < 4; ++i)
#pragma unroll
    for (int j = 0; j < 4; ++j) { m_r[i][j] = -1e30f; l_r[i][j] = 0.f; }

  for (int it = 0; it < 7; ++it) {
    __syncthreads();  // previous tile consumed (covers akv_s/Vt-zero on it=0)
    // ---- stage 112 keys: K rows normalized; V transposed normalized ----
    for (int idx = t; idx < 112 * 24; idx += 256) {
      int row = idx / 24;
      int c4 = (idx % 24) * 4;
      ushort4 u4 = *(const ushort4*)&Ykv[((size_t)(b * NTOK + it * 112 + row)) * NKV + h * 96 + c4];
      unsigned short uu[4] = {u4.x, u4.y, u4.z, u4.w};
      if (c4 < KDIM) {
        unsigned short o[4];
#pragma unroll
        for (int i2 = 0; i2 < 4; ++i2)
          o[i2] = f2bf(bf2f(uu[i2]) * akv_s[c4 + i2] + ckv_s[c4 + i2]);
        *(ushort4*)&Kl[row][c4] = make_ushort4(o[0], o[1], o[2], o[3]);
      } else {
#pragma unroll
        for (int i2 = 0; i2 < 4; ++i2) {
          int ch = c4 + i2;
          Vt[ch - KDIM][row] = f2bf(bf2f(uu[i2]) * akv_s[ch] + ckv_s[ch]);
        }
      }
    }
    __syncthreads();

    for (int kt32 = 0; kt32 < 4; ++kt32) {
      const int kt0 = kt32 * 2;          // first 16-key subtile (always real)
      const bool real1 = (kt0 + 1) < 7;  // second subtile real?

      // K B-fragments (shared across q-tiles)
      bf16x8 kb0 = *(const bf16x8*)&Kl[kt0 * 16 + c][g * 8];
      bf16x8 kb1 = kb0;
      if (real1) kb1 = *(const bf16x8*)&Kl[(kt0 + 1) * 16 + c][g * 8];

      // V B-fragments (shared across q-tiles): Vt[d][key]
      bf16x8 vb[4];
#pragma unroll
      for (int d = 0; d < 4; ++d)
        vb[d] = *(const bf16x8*)&Vt[d * 16 + c][kt32 * 32 + g * 8];

#pragma unroll
      for (int i = 0; i < 4; ++i) {
        if (i >= nt) break;
        const int tile = wave + i * 4;

        f32x4 S0 = __builtin_amdgcn_mfma_f32_16x16x32_bf16(
            qf[i], kb0, f32x4{0.f, 0.f, 0.f, 0.f}, 0, 0, 0);
        f32x4 S1;
        if (real1)
          S1 = __builtin_amdgcn_mfma_f32_16x16x32_bf16(
              qf[i], kb1, f32x4{0.f, 0.f, 0.f, 0.f}, 0, 0, 0);
        else
          S1 = f32x4{-1e30f, -1e30f, -1e30f, -1e30f};

        // bias add (fragment-layout, coalesced)
        {
          const size_t bi0 = (((size_t)(h * 49 + it * 7 + kt0) * 13 + tile) * 64 + lane);
          ushort4 b0 = *(const ushort4*)&BiasF[bi0 * 4];
          S0[0] += bf2f(b0.x); S0[1] += bf2f(b0.y);
          S0[2] += bf2f(b0.z); S0[3] += bf2f(b0.w);
          if (real1) {
            const size_t bi1 = (((size_t)(h * 49 + it * 7 + kt0 + 1) * 13 + tile) * 64 + lane);
            ushort4 b1 = *(const ushort4*)&BiasF[bi1 * 4];
            S1[0] += bf2f(b1.x); S1[1] += bf2f(b1.y);
            S1[2] += bf2f(b1.z); S1[3] += bf2f(b1.w);
          }
        }

        // row max over this 32-key group (16 lanes per row)
        float mx[4];
#pragma unroll
        for (int j = 0; j < 4; ++j) {
          float v = fmaxf(S0[j], S1[j]);
          v = fmaxf(v, __shfl_xor(v, 1));
          v = fmaxf(v, __shfl_xor(v, 2));
          v = fmaxf(v, __shfl_xor(v, 4));
          v = fmaxf(v, __shfl_xor(v, 8));
          mx[j] = v;
        }

        // defer-max rescale
#pragma unroll
        for (int j = 0; j < 4; ++j) {
          if (mx[j] > m_r[i][j] + 8.f) {
            float corr = __builtin_exp2f(m_r[i][j] - mx[j]);
            l_r[i][j] *= corr;
#pragma unroll
            for (int d = 0; d < 4; ++d) acc[i][d][j] *= corr;
            m_r[i][j] = mx[j];
          }
        }

        // p = exp2(S - m), distributed l, write P^T to per-wave LDS
#pragma unroll
        for (int j = 0; j < 4; ++j) {
          float p0 = __builtin_exp2f(S0[j] - m_r[i][j]);
          float p1 = __builtin_exp2f(S1[j] - m_r[i][j]);  // 0 for phantom
          l_r[i][j] += p0 + p1;
          Pl[wave][g * 4 + j][c] = f2bf(p0);
          Pl[wave][g * 4 + j][16 + c] = f2bf(p1);
        }

        // PV: A = P (lane: q=c, key-slot g*8+j), B = Vt
        bf16x8 pa = *(const bf16x8*)&Pl[wave][c][g * 8];
#pragma unroll
        for (int d = 0; d < 4; ++d)
          acc[i][d] = __builtin_amdgcn_mfma_f32_16x16x32_bf16(pa, vb[d], acc[i][d], 0, 0, 0);
      }
    }
  }

  // ---- finalize: row-sum l, normalize, hswish, store ----
#pragma unroll
  for (int i = 0; i < 4; ++i) {
    if (i >= nt) break;
    const int tile = wave + i * 4;
#pragma unroll
    for (int j = 0; j < 4; ++j) {
      float ls = l_r[i][j];
      ls += __shfl_xor(ls, 1);
      ls += __shfl_xor(ls, 2);
      ls += __shfl_xor(ls, 4);
      ls += __shfl_xor(ls, 8);
      const int ql = tile * 16 + g * 4 + j;
      if (ql < NTOKH) {
        float inv = 1.f / ls;
        float* op = &Out[((size_t)b * NTOKH + ql) * DH + h * VDIM];
#pragma unroll
        for (int d = 0; d < 4; ++d)
          op[d * 16 + c] = hswish(acc[i][d][j] * inv);
      }
    }
  }
}

// ------------------------------------------------------------------
__global__ void norm_out(const float* __restrict__ Yp, const float* __restrict__ Ap,
                         const float* __restrict__ Cp, float* __restrict__ out) {
  const int total = MQ * (NP / 4);
  for (int idx = blockIdx.x * blockDim.x + threadIdx.x; idx < total;
       idx += gridDim.x * blockDim.x) {
    int c4 = (idx % (NP / 4)) * 4;
    float4 y = ((const float4*)Yp)[idx];
    float4 o;
    o.x = y.x * Ap[c4 + 0] + Cp[c4 + 0];
    o.y = y.y * Ap[c4 + 1] + Cp[c4 + 1];
    o.z = y.z * Ap[c4 + 2] + Cp[c4 + 2];
    o.w = y.w * Ap[c4 + 3] + Cp[c4 + 3];
    ((float4*)out)[idx] = o;
  }
}

// ------------------------------------------------------------------
extern "C" void kernel_launch(void* const* d_in, const int* in_sizes, int n_in,
                              void* d_out, int out_size, void* d_ws, size_t ws_size,
                              hipStream_t stream) {
  const float* x      = (const float*)d_in[0];
  const float* W_kv   = (const float*)d_in[1];
  const float* g_kv   = (const float*)d_in[2];
  const float* b_kv   = (const float*)d_in[3];
  const float* W_q    = (const float*)d_in[4];
  const float* g_q    = (const float*)d_in[5];
  const float* b_q    = (const float*)d_in[6];
  const float* W_proj = (const float*)d_in[7];
  const float* g_proj = (const float*)d_in[8];
  const float* b_proj = (const float*)d_in[9];
  const float* attn_b = (const float*)d_in[10];
  const int* bias_idxs = (const int*)d_in[11];
  const int n_off = in_sizes[10] / NH;

  // ---- workspace layout: round-2/4 proven footprint (BiasF fits in BiasT slot) ----
  float* ws = (float*)d_ws;
  size_t off = 0;
  unsigned short* Ykv = (unsigned short*)(ws + off);  off += (size_t)MKV * NKV / 2;
  float* Yq = ws + off;                               off += (size_t)MQ * NQC;
  float* Out = ws + off;                              off += (size_t)MQ * DH;
  unsigned short* BiasF = (unsigned short*)(ws + off); off += (size_t)NH * NTOK * NTOKH;  // uses half
  double2* part = (double2*)(ws + off);               off += (size_t)64 * NKV * 4;
  float* AC = ws + off;                               off += 2 * NKV + 2 * NQC + 2 * NP;

  float* Akv = AC;            float* Ckv = AC + NKV;
  float* Aq = AC + 2 * NKV;   float* Cq = AC + 2 * NKV + NQC;
  float* Ap = AC + 2 * NKV + 2 * NQC;
  float* Cp = AC + 2 * NKV + 2 * NQC + NP;

  // W splits aliased into Out (consumed before attn writes Out)
  unsigned short* WkvH = (unsigned short*)Out;
  unsigned short* WkvL = WkvH + (size_t)NKV * CIN;
  unsigned short* WqH  = WkvL + (size_t)NKV * CIN;
  unsigned short* WqL  = WqH + (size_t)NQC * CIN;

  float* Yp = ws;  // aliases Ykv (dead after attention)

  make_biasF<<<dim3(2048), dim3(256), 0, stream>>>(attn_b, bias_idxs, BiasF, n_off);
  split_w<<<dim3((NKV * CIN / 8 + 255) / 256), dim3(256), 0, stream>>>(W_kv, WkvH, WkvL, NKV * CIN / 8);
  split_w<<<dim3((NQC * CIN / 8 + 255) / 256), dim3(256), 0, stream>>>(W_q, WqH, WqL, NQC * CIN / 8);

  gemm_mfma<1, 0><<<dim3(MKV / 128, NKV / 128), dim3(256), 0, stream>>>(
      x, WkvH, WkvL, nullptr, Ykv, MKV, NKV, CIN);
  gemm_mfma<0, 1><<<dim3(MQ / 128, NQC / 128), dim3(256), 0, stream>>>(
      x, WqH, WqL, Yq, nullptr, MQ, NQC, CIN);

  col_stats_partial<unsigned short><<<dim3(NKV / 64, 64), dim3(256), 0, stream>>>(Ykv, part, MKV, NKV);
  col_stats_finalize<<<dim3(NKV / 256), dim3(256), 0, stream>>>(part, g_kv, b_kv, Akv, Ckv, NKV, MKV, 1.0f);
  col_stats_partial<float><<<dim3(NQC / 64, 64), dim3(256), 0, stream>>>(Yq, part, MQ, NQC);
  const float qmul = 0.17677669529663687f * LOG2E;  // KD^-0.5 * log2(e)
  col_stats_finalize<<<dim3(NQC / 256), dim3(256), 0, stream>>>(part, g_q, b_q, Aq, Cq, NQC, MQ, qmul);

  attn_mfma<<<dim3(NB, NH), dim3(256), 0, stream>>>(Ykv, Yq, BiasF, Akv, Ckv, Aq, Cq, Out);

  gemm_nt<<<dim3(MQ / 128, NP / 128), dim3(256), 0, stream>>>(Out, W_proj, Yp, MQ, NP, DH);
  col_stats_partial<float><<<dim3(NP / 64, 64), dim3(256), 0, stream>>>(Yp, part, MQ, NP);
  col_stats_finalize<<<dim3(NP / 256), dim3(256), 0, stream>>>(part, g_proj, b_proj, Ap, Cp, NP, MQ, 1.0f);

  norm_out<<<dim3(2048), dim3(256), 0, stream>>>(Yp, Ap, Cp, (float*)d_out);
}

// Round 7
// 1074.818 us; speedup vs baseline: 3.2068x; 1.3027x over previous
//
#include <hip/hip_runtime.h>
#include <math.h>
#include <type_traits>

#define RESF 28
#define RESH 14
#define NH 16
#define KDIM 32
#define VDIM 64
#define CIN 512
#define NKV 1536   // NH*(KDIM+VDIM)
#define NQC 512    // NH*KDIM
#define NP 768
#define DH 1024    // NH*VDIM
#define NTOK 784
#define NTOKH 196
#define NB 64
#define MKV (NB*NTOK)    // 50176
#define MQ  (NB*NTOKH)   // 12544
#define BN_EPS 1e-5f
#define LOG2E 1.44269504088896f

typedef __attribute__((ext_vector_type(8))) short bf16x8;
typedef __attribute__((ext_vector_type(4))) float f32x4;

// ---------------- bf16 helpers (raw ushort bits) ----------------
__device__ inline unsigned short f2bf(float f) {  // RNE
  unsigned int u = __float_as_uint(f);
  unsigned int r = u + 0x7fffu + ((u >> 16) & 1u);
  return (unsigned short)(r >> 16);
}
__device__ inline float bf2f(unsigned short h) {
  return __uint_as_float(((unsigned int)h) << 16);
}

// split 8 floats -> packed bf16 hi (RNE) and lo (truncated residual)
__device__ inline void split8(const float4 f0, const float4 f1, uint4& hi, uint4& lo) {
  float f[8] = {f0.x, f0.y, f0.z, f0.w, f1.x, f1.y, f1.z, f1.w};
  unsigned hh[8], ll[8];
#pragma unroll
  for (int i = 0; i < 8; ++i) {
    unsigned u = __float_as_uint(f[i]);
    unsigned r = u + 0x7fffu + ((u >> 16) & 1u);
    unsigned h = r >> 16;
    hh[i] = h;
    float rf = f[i] - __uint_as_float(h << 16);
    ll[i] = __float_as_uint(rf) >> 16;
  }
  hi = make_uint4(hh[0] | (hh[1] << 16), hh[2] | (hh[3] << 16),
                  hh[4] | (hh[5] << 16), hh[6] | (hh[7] << 16));
  lo = make_uint4(ll[0] | (ll[1] << 16), ll[2] | (ll[3] << 16),
                  ll[4] | (ll[5] << 16), ll[6] | (ll[7] << 16));
}

// ------------------------------------------------------------------
__global__ void split_w(const float* __restrict__ src, unsigned short* __restrict__ hi,
                        unsigned short* __restrict__ lo, int n8) {
  int i = blockIdx.x * blockDim.x + threadIdx.x;
  if (i >= n8) return;
  const float4* s = (const float4*)src;
  float4 f0 = s[i * 2], f1 = s[i * 2 + 1];
  uint4 h, l;
  split8(f0, f1, h, l);
  ((uint4*)hi)[i] = h;
  ((uint4*)lo)[i] = l;
}

// ------------------------------------------------------------------
// Bias in MFMA fragment layout (bf16):
// BiasF[(((h*49 + kt)*13 + qt)*64 + lane)*4 + j] =
//   bias(q = qt*16 + (lane>>4)*4 + j, key = kt*16 + (lane&15)) * LOG2E
// ------------------------------------------------------------------
__global__ void make_biasF(const float* __restrict__ ab, const int* __restrict__ idxs,
                           unsigned short* __restrict__ biasF, int n_off) {
  const int total = NH * 49 * 13 * 64 * 4;  // 2,609,152
  for (int e = blockIdx.x * blockDim.x + threadIdx.x; e < total;
       e += gridDim.x * blockDim.x) {
    int j = e & 3;
    int lane = (e >> 2) & 63;
    int rest = e >> 8;
    int qt = rest % 13;
    int rest2 = rest / 13;
    int kt = rest2 % 49;
    int h = rest2 / 49;
    int q = qt * 16 + (lane >> 4) * 4 + j;
    int key = kt * 16 + (lane & 15);
    float v = 0.f;
    if (q < NTOKH) v = ab[(size_t)h * n_off + idxs[q * NTOK + key]] * LOG2E;
    biasF[e] = f2bf(v);
  }
}

// ------------------------------------------------------------------
// MFMA GEMM, 3-way bf16 split (round-4/6 verified).
// C[m,n] = sum_k A[m,k]*B[n,k]; A fp32 (split on the fly), B pre-split.
// 128x128 tile, BK=32, 4 waves (2x2), 4x4 16x16x32 frags per wave.
// ------------------------------------------------------------------
template <int OUT_BF16, int GATHER>
__global__ __launch_bounds__(256)
void gemm_mfma(const float* __restrict__ Af,
               const unsigned short* __restrict__ BhG, const unsigned short* __restrict__ BlG,
               float* __restrict__ Cf, unsigned short* __restrict__ Cb,
               int M, int N, int K) {
  __shared__ unsigned short Ah[128][40], Al[128][40], Bh[128][40], Bl[128][40];
  const int t = threadIdx.x;
  const int m0 = blockIdx.x * 128, n0 = blockIdx.y * 128;
  const int sr = t >> 1, sc = (t & 1) * 16;
  int arow = m0 + sr;
  if (GATHER) {
    int bb = arow / NTOKH, r = arow - bb * NTOKH;
    int i = r / RESH, j = r - i * RESH;
    arow = bb * NTOK + i * (2 * RESF) + j * 2;
  }
  const int brow = n0 + sr;

  uint4 sAh0, sAh1, sAl0, sAl1, sBh0, sBh1, sBl0, sBl1;

  auto LOADSTAGE = [&](int k0) {
    const float* ap = Af + (size_t)arow * K + k0 + sc;
    float4 a0 = *(const float4*)ap;
    float4 a1 = *(const float4*)(ap + 4);
    float4 a2 = *(const float4*)(ap + 8);
    float4 a3 = *(const float4*)(ap + 12);
    split8(a0, a1, sAh0, sAl0);
    split8(a2, a3, sAh1, sAl1);
    const size_t ib = (size_t)brow * K + k0 + sc;
    sBh0 = *(const uint4*)&BhG[ib];
    sBh1 = *(const uint4*)&BhG[ib + 8];
    sBl0 = *(const uint4*)&BlG[ib];
    sBl1 = *(const uint4*)&BlG[ib + 8];
  };
  auto WRITESTAGE = [&]() {
    *(uint4*)&Ah[sr][sc] = sAh0;  *(uint4*)&Ah[sr][sc + 8] = sAh1;
    *(uint4*)&Al[sr][sc] = sAl0;  *(uint4*)&Al[sr][sc + 8] = sAl1;
    *(uint4*)&Bh[sr][sc] = sBh0;  *(uint4*)&Bh[sr][sc + 8] = sBh1;
    *(uint4*)&Bl[sr][sc] = sBl0;  *(uint4*)&Bl[sr][sc + 8] = sBl1;
  };

  const int wave = t >> 6, lane = t & 63;
  const int wm64 = (wave >> 1) * 64, wn64 = (wave & 1) * 64;
  const int fr = lane & 15, fg8 = (lane >> 4) * 8;

  f32x4 acc[4][4];
#pragma unroll
  for (int i = 0; i < 4; ++i)
#pragma unroll
    for (int j = 0; j < 4; ++j) acc[i][j] = f32x4{0.f, 0.f, 0.f, 0.f};

  const int nK = K / 32;
  LOADSTAGE(0);
  for (int kt = 0; kt < nK; ++kt) {
    __syncthreads();
    WRITESTAGE();
    __syncthreads();
    if (kt + 1 < nK) LOADSTAGE((kt + 1) * 32);
    bf16x8 ah[4], al[4];
#pragma unroll
    for (int fm = 0; fm < 4; ++fm) {
      ah[fm] = *(const bf16x8*)&Ah[wm64 + fm * 16 + fr][fg8];
      al[fm] = *(const bf16x8*)&Al[wm64 + fm * 16 + fr][fg8];
    }
#pragma unroll
    for (int fn = 0; fn < 4; ++fn) {
      bf16x8 bh = *(const bf16x8*)&Bh[wn64 + fn * 16 + fr][fg8];
      bf16x8 bl = *(const bf16x8*)&Bl[wn64 + fn * 16 + fr][fg8];
#pragma unroll
      for (int fm = 0; fm < 4; ++fm) {
        acc[fm][fn] = __builtin_amdgcn_mfma_f32_16x16x32_bf16(ah[fm], bh, acc[fm][fn], 0, 0, 0);
        acc[fm][fn] = __builtin_amdgcn_mfma_f32_16x16x32_bf16(al[fm], bh, acc[fm][fn], 0, 0, 0);
        acc[fm][fn] = __builtin_amdgcn_mfma_f32_16x16x32_bf16(ah[fm], bl, acc[fm][fn], 0, 0, 0);
      }
    }
  }

#pragma unroll
  for (int fm = 0; fm < 4; ++fm) {
    const int row0 = m0 + wm64 + fm * 16 + (lane >> 4) * 4;
#pragma unroll
    for (int fn = 0; fn < 4; ++fn) {
      const int col = n0 + wn64 + fn * 16 + fr;
#pragma unroll
      for (int j = 0; j < 4; ++j) {
        const size_t off = (size_t)(row0 + j) * N + col;
        if (OUT_BF16) Cb[off] = f2bf(acc[fm][fn][j]);
        else Cf[off] = acc[fm][fn][j];
      }
    }
  }
}

// ------------------------------------------------------------------
// Column stats (two stage), round-2 verified.
// ------------------------------------------------------------------
template <typename TY>
__global__ void col_stats_partial(const TY* __restrict__ Y, double2* __restrict__ part,
                                  int M, int NC) {
  const int col = blockIdx.x * 64 + (threadIdx.x & 63);
  const int rs = threadIdx.x >> 6;
  const int chunk = blockIdx.y;
  const int rpc = (M + 63) / 64;
  const int r0 = chunk * rpc;
  const int r1 = (r0 + rpc < M) ? (r0 + rpc) : M;
  double s = 0.0, s2 = 0.0;
  for (int r = r0 + rs; r < r1; r += 4) {
    float v;
    if constexpr (std::is_same<TY, float>::value) v = Y[(size_t)r * NC + col];
    else v = bf2f(Y[(size_t)r * NC + col]);
    s += (double)v;
    s2 += (double)v * (double)v;
  }
  __shared__ double sh[2][4][64];
  sh[0][rs][threadIdx.x & 63] = s;
  sh[1][rs][threadIdx.x & 63] = s2;
  __syncthreads();
  if (threadIdx.x < 64) {
    int c = threadIdx.x;
    double ts = sh[0][0][c] + sh[0][1][c] + sh[0][2][c] + sh[0][3][c];
    double t2 = sh[1][0][c] + sh[1][1][c] + sh[1][2][c] + sh[1][3][c];
    part[(size_t)chunk * NC + col] = make_double2(ts, t2);
  }
}

__global__ void col_stats_finalize(const double2* __restrict__ part,
                                   const float* __restrict__ g, const float* __restrict__ bb,
                                   float* __restrict__ Aout, float* __restrict__ Cout,
                                   int NC, int M, float mul) {
  const int col = blockIdx.x * blockDim.x + threadIdx.x;
  if (col >= NC) return;
  double s = 0.0, s2 = 0.0;
  for (int ch = 0; ch < 64; ++ch) {
    double2 p = part[(size_t)ch * NC + col];
    s += p.x;
    s2 += p.y;
  }
  double mean = s / (double)M;
  double var = s2 / (double)M - mean * mean;
  double A0 = (double)g[col] / sqrt(var + (double)BN_EPS);
  Aout[col] = (float)(A0 * (double)mul);
  Cout[col] = (float)(((double)bb[col] - mean * A0) * (double)mul);
}

// ------------------------------------------------------------------
// MFMA flash attention (round-6 verified). One block per (b,h), 4 waves.
// ------------------------------------------------------------------
__device__ inline float hswish(float x) {
  float r = fminf(fmaxf(x + 3.f, 0.f), 6.f);
  return x * r * (1.f / 6.f);
}

__global__ __launch_bounds__(256)
void attn_mfma(const unsigned short* __restrict__ Ykv, const float* __restrict__ Yq,
               const unsigned short* __restrict__ BiasF,
               const float* __restrict__ Akv, const float* __restrict__ Ckv,
               const float* __restrict__ Aq, const float* __restrict__ Cq,
               float* __restrict__ Out) {
  const int b = blockIdx.x, h = blockIdx.y;
  const int t = threadIdx.x;
  const int wave = t >> 6, lane = t & 63;
  const int c = lane & 15, g = lane >> 4;  // fragment col / k-group

  __shared__ unsigned short Kl[112][40];      // [key][kdim]
  __shared__ unsigned short Vt[64][136];      // [d][key] (transposed V)
  __shared__ unsigned short Pl[4][16][40];    // per-wave P transpose buffer
  __shared__ float akv_s[96], ckv_s[96];

  if (t < 96) {
    akv_s[t] = Akv[h * 96 + t];
    ckv_s[t] = Ckv[h * 96 + t];
  }
  // Zero Vt's tail columns: kt32=3 reads keys 96..127 but only 112 keys are
  // staged; uninitialized LDS bits could be NaN and 0*NaN = NaN in MFMA.
  for (int idx = t; idx < 64 * 24; idx += 256)
    Vt[idx / 24][112 + (idx % 24)] = 0;

  const int nt = (wave == 0) ? 4 : 3;  // q-tiles: wave + i*4

  // ---- Q fragments (A-operand): lane holds Q[q=c][kd=g*8+j] ----
  bf16x8 qf[4];
#pragma unroll
  for (int i = 0; i < 4; ++i) {
    if (i >= nt) break;
    const int tile = wave + i * 4;
    const int ql = tile * 16 + c;
    bf16x8 qv = {0, 0, 0, 0, 0, 0, 0, 0};
    if (ql < NTOKH) {
      const int c0 = h * KDIM + g * 8;
      const float* qp = &Yq[((size_t)b * NTOKH + ql) * NQC + c0];
      float4 a0 = *(const float4*)qp;
      float4 a1 = *(const float4*)(qp + 4);
      float v[8] = {a0.x, a0.y, a0.z, a0.w, a1.x, a1.y, a1.z, a1.w};
#pragma unroll
      for (int jj = 0; jj < 8; ++jj)
        qv[jj] = (short)f2bf(v[jj] * Aq[c0 + jj] + Cq[c0 + jj]);
    }
    qf[i] = qv;
  }

  f32x4 acc[4][4];
  float m_r[4][4], l_r[4][4];
#pragma unroll
  for (int i = 0; i < 4; ++i)
#pragma unroll
    for (int d = 0; d < 4; ++d) acc[i][d] = f32x4{0.f, 0.f, 0.f, 0.f};
#pragma unroll
  for (int i = 0; i < 4; ++i)
#pragma unroll
    for (int j = 0; j < 4; ++j) { m_r[i][j] = -1e30f; l_r[i][j] = 0.f; }

  for (int it = 0; it < 7; ++it) {
    __syncthreads();  // previous tile consumed (covers akv_s/Vt-zero on it=0)
    // ---- stage 112 keys: K rows normalized; V transposed normalized ----
    for (int idx = t; idx < 112 * 24; idx += 256) {
      int row = idx / 24;
      int c4 = (idx % 24) * 4;
      ushort4 u4 = *(const ushort4*)&Ykv[((size_t)(b * NTOK + it * 112 + row)) * NKV + h * 96 + c4];
      unsigned short uu[4] = {u4.x, u4.y, u4.z, u4.w};
      if (c4 < KDIM) {
        unsigned short o[4];
#pragma unroll
        for (int i2 = 0; i2 < 4; ++i2)
          o[i2] = f2bf(bf2f(uu[i2]) * akv_s[c4 + i2] + ckv_s[c4 + i2]);
        *(ushort4*)&Kl[row][c4] = make_ushort4(o[0], o[1], o[2], o[3]);
      } else {
#pragma unroll
        for (int i2 = 0; i2 < 4; ++i2) {
          int ch = c4 + i2;
          Vt[ch - KDIM][row] = f2bf(bf2f(uu[i2]) * akv_s[ch] + ckv_s[ch]);
        }
      }
    }
    __syncthreads();

    for (int kt32 = 0; kt32 < 4; ++kt32) {
      const int kt0 = kt32 * 2;          // first 16-key subtile (always real)
      const bool real1 = (kt0 + 1) < 7;  // second subtile real?

      // K B-fragments (shared across q-tiles)
      bf16x8 kb0 = *(const bf16x8*)&Kl[kt0 * 16 + c][g * 8];
      bf16x8 kb1 = kb0;
      if (real1) kb1 = *(const bf16x8*)&Kl[(kt0 + 1) * 16 + c][g * 8];

      // V B-fragments (shared across q-tiles): Vt[d][key]
      bf16x8 vb[4];
#pragma unroll
      for (int d = 0; d < 4; ++d)
        vb[d] = *(const bf16x8*)&Vt[d * 16 + c][kt32 * 32 + g * 8];

#pragma unroll
      for (int i = 0; i < 4; ++i) {
        if (i >= nt) break;
        const int tile = wave + i * 4;

        f32x4 S0 = __builtin_amdgcn_mfma_f32_16x16x32_bf16(
            qf[i], kb0, f32x4{0.f, 0.f, 0.f, 0.f}, 0, 0, 0);
        f32x4 S1;
        if (real1)
          S1 = __builtin_amdgcn_mfma_f32_16x16x32_bf16(
              qf[i], kb1, f32x4{0.f, 0.f, 0.f, 0.f}, 0, 0, 0);
        else
          S1 = f32x4{-1e30f, -1e30f, -1e30f, -1e30f};

        // bias add (fragment-layout, coalesced)
        {
          const size_t bi0 = (((size_t)(h * 49 + it * 7 + kt0) * 13 + tile) * 64 + lane);
          ushort4 b0 = *(const ushort4*)&BiasF[bi0 * 4];
          S0[0] += bf2f(b0.x); S0[1] += bf2f(b0.y);
          S0[2] += bf2f(b0.z); S0[3] += bf2f(b0.w);
          if (real1) {
            const size_t bi1 = (((size_t)(h * 49 + it * 7 + kt0 + 1) * 13 + tile) * 64 + lane);
            ushort4 b1 = *(const ushort4*)&BiasF[bi1 * 4];
            S1[0] += bf2f(b1.x); S1[1] += bf2f(b1.y);
            S1[2] += bf2f(b1.z); S1[3] += bf2f(b1.w);
          }
        }

        // row max over this 32-key group (16 lanes per row)
        float mx[4];
#pragma unroll
        for (int j = 0; j < 4; ++j) {
          float v = fmaxf(S0[j], S1[j]);
          v = fmaxf(v, __shfl_xor(v, 1));
          v = fmaxf(v, __shfl_xor(v, 2));
          v = fmaxf(v, __shfl_xor(v, 4));
          v = fmaxf(v, __shfl_xor(v, 8));
          mx[j] = v;
        }

        // defer-max rescale
#pragma unroll
        for (int j = 0; j < 4; ++j) {
          if (mx[j] > m_r[i][j] + 8.f) {
            float corr = __builtin_exp2f(m_r[i][j] - mx[j]);
            l_r[i][j] *= corr;
#pragma unroll
            for (int d = 0; d < 4; ++d) acc[i][d][j] *= corr;
            m_r[i][j] = mx[j];
          }
        }

        // p = exp2(S - m), distributed l, write P^T to per-wave LDS
#pragma unroll
        for (int j = 0; j < 4; ++j) {
          float p0 = __builtin_exp2f(S0[j] - m_r[i][j]);
          float p1 = __builtin_exp2f(S1[j] - m_r[i][j]);  // 0 for phantom
          l_r[i][j] += p0 + p1;
          Pl[wave][g * 4 + j][c] = f2bf(p0);
          Pl[wave][g * 4 + j][16 + c] = f2bf(p1);
        }

        // PV: A = P (lane: q=c, key-slot g*8+j), B = Vt
        bf16x8 pa = *(const bf16x8*)&Pl[wave][c][g * 8];
#pragma unroll
        for (int d = 0; d < 4; ++d)
          acc[i][d] = __builtin_amdgcn_mfma_f32_16x16x32_bf16(pa, vb[d], acc[i][d], 0, 0, 0);
      }
    }
  }

  // ---- finalize: row-sum l, normalize, hswish, store ----
#pragma unroll
  for (int i = 0; i < 4; ++i) {
    if (i >= nt) break;
    const int tile = wave + i * 4;
#pragma unroll
    for (int j = 0; j < 4; ++j) {
      float ls = l_r[i][j];
      ls += __shfl_xor(ls, 1);
      ls += __shfl_xor(ls, 2);
      ls += __shfl_xor(ls, 4);
      ls += __shfl_xor(ls, 8);
      const int ql = tile * 16 + g * 4 + j;
      if (ql < NTOKH) {
        float inv = 1.f / ls;
        float* op = &Out[((size_t)b * NTOKH + ql) * DH + h * VDIM];
#pragma unroll
        for (int d = 0; d < 4; ++d)
          op[d * 16 + c] = hswish(acc[i][d][j] * inv);
      }
    }
  }
}

// ------------------------------------------------------------------
__global__ void norm_out(const float* __restrict__ Yp, const float* __restrict__ Ap,
                         const float* __restrict__ Cp, float* __restrict__ out) {
  const int total = MQ * (NP / 4);
  for (int idx = blockIdx.x * blockDim.x + threadIdx.x; idx < total;
       idx += gridDim.x * blockDim.x) {
    int c4 = (idx % (NP / 4)) * 4;
    float4 y = ((const float4*)Yp)[idx];
    float4 o;
    o.x = y.x * Ap[c4 + 0] + Cp[c4 + 0];
    o.y = y.y * Ap[c4 + 1] + Cp[c4 + 1];
    o.z = y.z * Ap[c4 + 2] + Cp[c4 + 2];
    o.w = y.w * Ap[c4 + 3] + Cp[c4 + 3];
    ((float4*)out)[idx] = o;
  }
}

// ------------------------------------------------------------------
extern "C" void kernel_launch(void* const* d_in, const int* in_sizes, int n_in,
                              void* d_out, int out_size, void* d_ws, size_t ws_size,
                              hipStream_t stream) {
  const float* x      = (const float*)d_in[0];
  const float* W_kv   = (const float*)d_in[1];
  const float* g_kv   = (const float*)d_in[2];
  const float* b_kv   = (const float*)d_in[3];
  const float* W_q    = (const float*)d_in[4];
  const float* g_q    = (const float*)d_in[5];
  const float* b_q    = (const float*)d_in[6];
  const float* W_proj = (const float*)d_in[7];
  const float* g_proj = (const float*)d_in[8];
  const float* b_proj = (const float*)d_in[9];
  const float* attn_b = (const float*)d_in[10];
  const int* bias_idxs = (const int*)d_in[11];
  const int n_off = in_sizes[10] / NH;

  // ---- workspace layout: round-2/4/6 proven footprint ----
  float* ws = (float*)d_ws;
  size_t off = 0;
  unsigned short* Ykv = (unsigned short*)(ws + off);  off += (size_t)MKV * NKV / 2;
  float* Yq = ws + off;                               off += (size_t)MQ * NQC;
  float* Out = ws + off;                              off += (size_t)MQ * DH;
  unsigned short* BiasF = (unsigned short*)(ws + off); off += (size_t)NH * NTOK * NTOKH;  // region holds 4.9M ush; BiasF uses 2.6M
  double2* part = (double2*)(ws + off);               off += (size_t)64 * NKV * 4;
  float* AC = ws + off;                               off += 2 * NKV + 2 * NQC + 2 * NP;

  float* Akv = AC;            float* Ckv = AC + NKV;
  float* Aq = AC + 2 * NKV;   float* Cq = AC + 2 * NKV + NQC;
  float* Ap = AC + 2 * NKV + 2 * NQC;
  float* Cp = AC + 2 * NKV + 2 * NQC + NP;

  // W_kv/W_q splits aliased into Out (consumed before attn writes Out)
  unsigned short* WkvH = (unsigned short*)Out;
  unsigned short* WkvL = WkvH + (size_t)NKV * CIN;
  unsigned short* WqH  = WkvL + (size_t)NKV * CIN;
  unsigned short* WqL  = WqH + (size_t)NQC * CIN;

  // W_proj split aliased into BiasF region (dead after attn; split_w for
  // proj is launched AFTER attn_mfma -> stream-ordered safe).
  // 2 x 786,432 ush = 1.57M ush < 4.9M ush available.
  unsigned short* WpH = BiasF;
  unsigned short* WpL = WpH + (size_t)NP * DH;

  float* Yp = ws;  // aliases Ykv (dead after attention)

  make_biasF<<<dim3(2048), dim3(256), 0, stream>>>(attn_b, bias_idxs, BiasF, n_off);
  split_w<<<dim3((NKV * CIN / 8 + 255) / 256), dim3(256), 0, stream>>>(W_kv, WkvH, WkvL, NKV * CIN / 8);
  split_w<<<dim3((NQC * CIN / 8 + 255) / 256), dim3(256), 0, stream>>>(W_q, WqH, WqL, NQC * CIN / 8);

  gemm_mfma<1, 0><<<dim3(MKV / 128, NKV / 128), dim3(256), 0, stream>>>(
      x, WkvH, WkvL, nullptr, Ykv, MKV, NKV, CIN);
  gemm_mfma<0, 1><<<dim3(MQ / 128, NQC / 128), dim3(256), 0, stream>>>(
      x, WqH, WqL, Yq, nullptr, MQ, NQC, CIN);

  col_stats_partial<unsigned short><<<dim3(NKV / 64, 64), dim3(256), 0, stream>>>(Ykv, part, MKV, NKV);
  col_stats_finalize<<<dim3(NKV / 256), dim3(256), 0, stream>>>(part, g_kv, b_kv, Akv, Ckv, NKV, MKV, 1.0f);
  col_stats_partial<float><<<dim3(NQC / 64, 64), dim3(256), 0, stream>>>(Yq, part, MQ, NQC);
  const float qmul = 0.17677669529663687f * LOG2E;  // KD^-0.5 * log2(e)
  col_stats_finalize<<<dim3(NQC / 256), dim3(256), 0, stream>>>(part, g_q, b_q, Aq, Cq, NQC, MQ, qmul);

  attn_mfma<<<dim3(NB, NH), dim3(256), 0, stream>>>(Ykv, Yq, BiasF, Akv, Ckv, Aq, Cq, Out);

  // proj: split W_proj (over dead BiasF), then MFMA GEMM (A=Out fp32 on-the-fly)
  split_w<<<dim3((NP * DH / 8 + 255) / 256), dim3(256), 0, stream>>>(W_proj, WpH, WpL, NP * DH / 8);
  gemm_mfma<0, 0><<<dim3(MQ / 128, NP / 128), dim3(256), 0, stream>>>(
      Out, WpH, WpL, Yp, nullptr, MQ, NP, DH);

  col_stats_partial<float><<<dim3(NP / 64, 64), dim3(256), 0, stream>>>(Yp, part, MQ, NP);
  col_stats_finalize<<<dim3(NP / 256), dim3(256), 0, stream>>>(part, g_proj, b_proj, Ap, Cp, NP, MQ, 1.0f);

  norm_out<<<dim3(2048), dim3(256), 0, stream>>>(Yp, Ap, Cp, (float*)d_out);
}